// Round 5
// baseline (1215.916 us; speedup 1.0000x reference)
//
#include <hip/hip_runtime.h>
#include <math.h>

#define GAIN 1.6778523489932886f     // 1/0.596
#define MPS  1.3130643285972254f     // 1/sqrt(0.7^2+0.3^2)

typedef __attribute__((ext_vector_type(8))) short short8;
typedef __attribute__((ext_vector_type(4))) short short4v;
typedef __attribute__((ext_vector_type(4))) float float4v;

__device__ __forceinline__ float silu_g(float x){
  float s = 1.0f/(1.0f + __expf(-x));
  return x*s*GAIN;
}
__device__ __forceinline__ short f2bf(float f){
  unsigned u = __builtin_bit_cast(unsigned, f);
  u += 0x7fffu + ((u >> 16) & 1u);
  return (short)(u >> 16);
}
__device__ __forceinline__ float bf2f(unsigned short h){
  return __builtin_bit_cast(float, ((unsigned)h) << 16);
}

// async global->LDS, 16B per lane (dest is wave-uniform base + lane*16)
typedef __attribute__((address_space(3))) unsigned int as3_uint;
typedef const __attribute__((address_space(1))) unsigned int as1_cuint;
__device__ __forceinline__ void gload16(const unsigned short* gsrc, unsigned short* ldst){
  __builtin_amdgcn_global_load_lds((as1_cuint*)gsrc, (as3_uint*)ldst, 16, 0, 0);
}

// ---------------- fused weight row-norm + bf16 cast (one wave per row) ----------------
struct NcEnt { const float* w; int O, K, dstOff; };
struct NcArgs { NcEnt e[16]; };

__global__ __launch_bounds__(64) void normcast_kernel(NcArgs na, unsigned short* __restrict__ wbf){
  int row = blockIdx.x;
  int base = 0; int i;
  for (i = 0; i < 16; i++){
    if (row < base + na.e[i].O) break;
    base += na.e[i].O;
  }
  if (i >= 16) return;
  int r = row - base; int K = na.e[i].K;
  const float* w = na.e[i].w + (long)r*K;
  unsigned short* dst = wbf + na.e[i].dstOff + (long)r*K;
  int tid = threadIdx.x;
  float s = 0.f;
  const bool v4 = ((K & 3) == 0);
  if (v4){
    for (int k = tid*4; k < K; k += 256){
      float4v v = *(const float4v*)&w[k];
      s += v[0]*v[0] + v[1]*v[1] + v[2]*v[2] + v[3]*v[3];
    }
  } else {
    for (int k = tid; k < K; k += 64){ float v = w[k]; s += v*v; }
  }
  for (int off = 32; off; off >>= 1) s += __shfl_down(s, off);
  float inv = rsqrtf(__shfl(s, 0) + 1e-8f);
  if (v4){
    for (int k = tid*4; k < K; k += 256){
      float4v v = *(const float4v*)&w[k];
      short4v o = { f2bf(v[0]*inv), f2bf(v[1]*inv), f2bf(v[2]*inv), f2bf(v[3]*inv) };
      *(short4v*)&dst[k] = o;
    }
  } else {
    for (int k = tid; k < K; k += 64) dst[k] = (unsigned short)f2bf(w[k]*inv);
  }
}

// ---------------- audio projection stats (one wave) ----------------
__global__ __launch_bounds__(64) void projstats_kernel(const float* __restrict__ pw, const float* __restrict__ pb,
                                                       float* __restrict__ S){
  int t = threadIdx.x;
  float p = pw[t], q = pb[t];
  float s1 = p*p, s2 = p*q, s3 = q*q;
  for (int off = 32; off; off >>= 1){
    s1 += __shfl_down(s1, off); s2 += __shfl_down(s2, off); s3 += __shfl_down(s3, off);
  }
  if (t == 0){ S[0] = s1; S[1] = s2; S[2] = s3; }
}

// ---------------- b0 inverse pixel-norm (closed form, element-wise 4-wide) ----------------
__global__ __launch_bounds__(256) void invn_audio_kernel(const float* __restrict__ audio, const float* __restrict__ S,
                                                         float* __restrict__ invn){
  long i = blockIdx.x*256 + threadIdx.x;
  if (i >= (2L*128*2048)/4) return;
  long e = i*4;
  float S1 = S[0], S2 = S[1], S3 = S[2];
  float4v a = *(const float4v*)&audio[e];
  float4v o;
  #pragma unroll
  for (int j = 0; j < 4; j++) o[j] = rsqrtf((a[j]*a[j]*S1 + 2.f*a[j]*S2 + S3)/64.f + 1e-4f);
  *(float4v*)&invn[e] = o;
}

// ---------------- pixel-norm reduce (fp32 or bf16 source) ----------------
template<int G, bool BF>
__global__ __launch_bounds__(256) void invn_reduce_kernel(const void* __restrict__ Xv, float* __restrict__ invn,
                                                          int C, int F){
  constexpr int L = 256/G;
  int t = threadIdx.x; int cs = t / L; int li = t % L;
  long pos = (long)blockIdx.x*L + li;
  int bf = (int)(pos >> 11); int l = (int)(pos & 2047);
  int b = bf / F; int f = bf - b*F;
  long base = ((long)b*C*F + f)*2048 + l;
  long stride = (long)F*2048;
  float s = 0.f;
  if (BF){
    const unsigned short* X = (const unsigned short*)Xv;
    for (int c = cs; c < C; c += G){ float v = bf2f(X[base + (long)c*stride]); s += v*v; }
  } else {
    const float* X = (const float*)Xv;
    for (int c = cs; c < C; c += G){ float v = X[base + (long)c*stride]; s += v*v; }
  }
  __shared__ float red[256];
  red[t] = s; __syncthreads();
  #pragma unroll
  for (int off = G/2; off > 0; off >>= 1){
    if (cs < off) red[t] += red[t + off*L];
    __syncthreads();
  }
  if (cs == 0) invn[pos] = rsqrtf(red[li]/(float)C + 1e-4f);
}

// ---------------- pixel-norm apply (fp32 or bf16 source) ----------------
template<bool SILU, bool BF>
__global__ __launch_bounds__(256) void applynorm_kernel(const void* __restrict__ Xv, const float* __restrict__ invn,
                                                        unsigned short* __restrict__ XB, int C, int F, long total4){
  long i = blockIdx.x*256 + threadIdx.x;
  if (i >= total4) return;
  long e = i*4;
  int l = (int)(e & 2047); long r = e >> 11;      // r = (b*C + c)*F + f
  int f = (int)(r % F); long bc = r / F; int b = (int)(bc / C);
  float4v x;
  if (BF){
    short4v u = *(const short4v*)((const unsigned short*)Xv + e);
    x = (float4v){ bf2f((unsigned short)u[0]), bf2f((unsigned short)u[1]),
                   bf2f((unsigned short)u[2]), bf2f((unsigned short)u[3]) };
  } else {
    x = *(const float4v*)((const float*)Xv + e);
  }
  float4v iv = *(const float4v*)&invn[((long)b*F + f)*2048 + l];
  short4v o;
  #pragma unroll
  for (int j = 0; j < 4; j++){
    float v = x[j]*iv[j];
    o[j] = f2bf(SILU ? silu_g(v) : v);
  }
  *(short4v*)&XB[e] = o;
}

// ---------------- seq pixel-norm + transpose: SEQ f32 [b][512][l] -> XST bf16 [b][l][512] ----------------
__global__ __launch_bounds__(256) void normT_kernel(const float* __restrict__ SEQ,
                                                    const float* __restrict__ invn,
                                                    unsigned short* __restrict__ XST){
  __shared__ float tile[64][65];
  const int l0 = blockIdx.x*64, c0 = blockIdx.y*64, b = blockIdx.z;
  const int t = threadIdx.x;
  const int lr = (t & 15)*4;   // l offset within tile (float4)
  const int cr = t >> 4;       // c row, 16 per pass
  #pragma unroll
  for (int p = 0; p < 4; p++){
    int c = cr + p*16;
    float4v v = *(const float4v*)&SEQ[((long)(b*512 + c0 + c))*2048 + l0 + lr];
    tile[c][lr+0] = v[0]; tile[c][lr+1] = v[1]; tile[c][lr+2] = v[2]; tile[c][lr+3] = v[3];
  }
  __syncthreads();
  const int cc = (t & 7)*8;    // c offset within tile (8 wide)
  const int lw = t >> 3;       // l row, 32 per pass
  #pragma unroll
  for (int p = 0; p < 2; p++){
    int l = lw + p*32;
    float iv = invn[b*2048 + l0 + l];
    short8 o;
    #pragma unroll
    for (int j = 0; j < 8; j++) o[j] = f2bf(tile[cc+j][l] * iv);
    *(short8*)&XST[((long)(b*2048 + l0 + l))*512 + c0 + cc] = o;
  }
}

// ---------------- K-major fused GEMM for seq blocks ----------------
// A: [N][K] bf16 (normalized weights), B: [M][K] bf16 (M = b*2048 + l)
// EMODE 0 (gz): O1 = ZCh [b][2048][l]
// EMODE 1 (gh): n<1024 -> silu -> O1 = HST [b][l][1024] (packed), else raw -> O2 = G [b][1024][l]
// 3-buffer LDS, global_load_lds staging (pre-swizzled source + XOR-swizzled ds_read),
// counted vmcnt (8/4/0), raw s_barrier. LDS-transpose epilogue for coalesced stores.
struct GTArgs {
  const unsigned short* A;
  const unsigned short* B;
  unsigned short* O1;
  unsigned short* O2;
  int N, K;
};

template<int EMODE>
__global__ __launch_bounds__(256,2) void gemmT_kernel(GTArgs g){
  __shared__ __align__(16) char SMEMraw[49152];
  unsigned short (*Asm)[4096] = (unsigned short (*)[4096])SMEMraw;            // [3][128*32]
  unsigned short (*Bsm)[4096] = (unsigned short (*)[4096])(SMEMraw + 24576);
  const int t = threadIdx.x;
  const int lane = t & 63;
  const int wc = (t >> 7) & 1;        // N-half
  const int wsd = (t >> 6) & 1;       // M-half
  const int q = lane >> 4, r16 = lane & 15;
  const int m0 = blockIdx.x * 128;
  const int n0 = blockIdx.y * 128;
  const int K = g.K;

  const int r0 = t >> 2;
  const int c8 = (((t & 3) ^ ((r0 >> 1) & 3)) << 3);
  const unsigned short* Ap = g.A + (long)(n0 + r0)*K + c8;
  const unsigned short* Bp = g.B + (long)(m0 + r0)*K + c8;

  auto stage = [&](int bi, int k0){
    gload16(Ap + k0,           &Asm[bi][t*8]);
    gload16(Ap + 64*K + k0,    &Asm[bi][2048 + t*8]);
    gload16(Bp + k0,           &Bsm[bi][t*8]);
    gload16(Bp + 64*K + k0,    &Bsm[bi][2048 + t*8]);
  };

  float4v acc[4][4];
  #pragma unroll
  for (int i = 0; i < 4; i++)
    #pragma unroll
    for (int j = 0; j < 4; j++) acc[i][j] = (float4v){0.f,0.f,0.f,0.f};

  const int nit = K >> 5;
  stage(0, 0);
  stage(1, 32);

  const int qsw = ((q ^ ((r16 >> 1) & 3)) << 3);  // swizzled k-chunk for ds_read

  for (int it = 0; it < nit; ++it){
    if (it + 2 < nit){
      stage((it + 2) % 3, (it + 2) << 5);
      asm volatile("" ::: "memory");
      asm volatile("s_waitcnt vmcnt(8)" ::: "memory");
    } else if (it + 1 < nit){
      asm volatile("s_waitcnt vmcnt(4)" ::: "memory");
    } else {
      asm volatile("s_waitcnt vmcnt(0)" ::: "memory");
    }
    __builtin_amdgcn_s_barrier();
    asm volatile("" ::: "memory");

    const unsigned short* As = Asm[it % 3];
    const unsigned short* Bs = Bsm[it % 3];
    short8 afr[4], bfr[4];
    #pragma unroll
    for (int i = 0; i < 4; i++) afr[i] = *(const short8*)&As[(wc*64 + i*16 + r16)*32 + qsw];
    #pragma unroll
    for (int j = 0; j < 4; j++) bfr[j] = *(const short8*)&Bs[(wsd*64 + j*16 + r16)*32 + qsw];
    #pragma unroll
    for (int i = 0; i < 4; i++)
      #pragma unroll
      for (int j = 0; j < 4; j++)
        acc[i][j] = __builtin_amdgcn_mfma_f32_16x16x32_bf16(afr[i], bfr[j], acc[i][j], 0, 0, 0);

    asm volatile("" ::: "memory");
    __builtin_amdgcn_s_barrier();
  }

  // ---- LDS-transpose epilogue ----
  if (EMODE == 1 && n0 < 1024){
    // h-half: output HST[b][l][1024] -> per-lane 8-n runs (128B-contiguous per 8 lanes)
    float* Cf = (float*)SMEMraw;    // [128][68]
    #pragma unroll
    for (int h = 0; h < 2; h++){
      __syncthreads();
      if (wc == h){
        #pragma unroll
        for (int j = 0; j < 4; j++){
          int m = wsd*64 + j*16 + r16;
          #pragma unroll
          for (int i = 0; i < 4; i++)
            *(float4v*)&Cf[m*68 + i*16 + q*4] = acc[i][j];
        }
      }
      __syncthreads();
      #pragma unroll
      for (int p = 0; p < 4; p++){
        int m = (t >> 3) + p*32;
        int n8 = (t & 7)*8;
        int gm = m0 + m; int b = gm >> 11, l = gm & 2047;
        float4v v0 = *(const float4v*)&Cf[m*68 + n8];
        float4v v1 = *(const float4v*)&Cf[m*68 + n8 + 4];
        short8 o;
        #pragma unroll
        for (int e = 0; e < 4; e++){ o[e] = f2bf(silu_g(v0[e])); o[e+4] = f2bf(silu_g(v1[e])); }
        *(short8*)&g.O1[((long)(b*2048 + l))*1024 + (n0 + h*64 + n8)] = o;
      }
    }
  } else {
    // [n][l] outputs: per-lane 8-l runs (256B-contiguous per 16 lanes)
    float* Csm = (float*)SMEMraw;   // [32][132]
    #pragma unroll
    for (int qtr = 0; qtr < 4; qtr++){
      __syncthreads();
      if (wc == (qtr >> 1)){
        #pragma unroll
        for (int ii = 0; ii < 2; ii++){
          int i = (qtr & 1)*2 + ii;
          #pragma unroll
          for (int j = 0; j < 4; j++){
            int m = wsd*64 + j*16 + r16;
            #pragma unroll
            for (int rg = 0; rg < 4; rg++)
              Csm[(ii*16 + q*4 + rg)*132 + m] = acc[i][j][rg];
          }
        }
      }
      __syncthreads();
      #pragma unroll
      for (int sp = 0; sp < 2; sp++){
        int nrow = (t >> 4) + sp*16;
        int n = n0 + qtr*32 + nrow;
        int m8 = (t & 15)*8;
        int gm = m0 + m8; int b = gm >> 11, l = gm & 2047;
        float4v v0 = *(const float4v*)&Csm[nrow*132 + m8];
        float4v v1 = *(const float4v*)&Csm[nrow*132 + m8 + 4];
        short8 o;
        #pragma unroll
        for (int e = 0; e < 4; e++){ o[e] = f2bf(v0[e]); o[e+4] = f2bf(v1[e]); }
        if (EMODE == 1) *(short8*)&g.O2[((long)(b*1024 + (n - 1024)))*2048 + l] = o;
        else            *(short8*)&g.O1[((long)(b*2048 + n))*2048 + l] = o;
      }
    }
  }
}

// ---------------- bf16 MFMA fused GEMM (128x128 tile, register-prefetched K-loop) ----------------
// BMODE: 0 = bf16 copy (windowed/zero-padded), 2 = audio closed-form (b0 conv1)
// EMODE: 1 bf16 store, 2 mp_add auxXH(bf16)->bf16, 3 mp_add audio-proj->bf16
struct GemmArgs {
  const unsigned short* A;       // pre-normalized bf16 weights, row-major K
  const unsigned short* Bh;      // bf16 B source
  const float* invn; const float* audio;
  const float* pw; const float* pb;
  const unsigned short* auxXH;
  unsigned short* CoutH; unsigned short* Cout2H;
  int N, K, Fdim, Lw, lq0, BLw, Bl0, CLw, Cl0, Nsto, Fsrc;
};

template<int BMODE, int EMODE>
__global__ __launch_bounds__(256,2) void mgemm_kernel(GemmArgs g){
  __shared__ __align__(16) char SMEMraw[20480];
  unsigned short* Asm = (unsigned short*)SMEMraw;       // [128*40]
  unsigned short* Bsm = Asm + 128*40;                   // [128*40]
  const int t = threadIdx.x;
  const int lane = t & 63;
  const int wave = t >> 6;
  const int wc = wave >> 1, wsd = wave & 1;
  const int q = lane >> 4, r16 = lane & 15;
  const int s0 = blockIdx.x * 128;
  const int n0 = blockIdx.y * 128;
  const int FL = g.Fdim * g.Lw;

  // A staging mapping
  const int ar = t >> 1, ah = t & 1;
  const int an = n0 + ar;
  const bool aval = an < g.N;
  const unsigned short* Aptr = g.A + (long)an*g.K + ah*16;

  // B staging mapping: (k-group kg 0..7 of 4k, m-group mg 0..31 of 4m)
  const int kg = t & 7, mg = t >> 3;
  const int mb = s0 + mg*4;
  int bcol = mb / FL; int rr = mb - bcol*FL;
  int fcol = (g.Fdim > 1) ? (rr / g.Lw) : 0;
  int labs = g.lq0 + (rr - fcol*g.Lw);
  const bool cv = (bcol < 2);
  bool lv[4];
  #pragma unroll
  for (int j = 0; j < 4; j++) lv[j] = cv && (labs + j >= 0) && (labs + j < 2048);
  const bool vec4 = cv && (labs >= 0) && (labs + 3 < 2048);
  const unsigned short* bbase = g.Bh;
  if (cv) bbase = g.Bh + ((long)(bcol*g.K)*g.Fsrc + fcol)*g.BLw + (labs - g.Bl0);
  const long kstep = (long)g.Fsrc * g.BLw;

  float invn4[4] = {0,0,0,0}, aud4[4] = {0,0,0,0};
  if (BMODE == 2){
    #pragma unroll
    for (int j = 0; j < 4; j++) if (lv[j]){
      invn4[j] = g.invn[(bcol*g.Fdim + fcol)*2048 + labs + j];
      aud4[j]  = g.audio[(bcol*128 + fcol)*2048 + labs + j];
    }
  }

  float4v acc[4][4];
  #pragma unroll
  for (int i = 0; i < 4; i++)
    #pragma unroll
    for (int j = 0; j < 4; j++) acc[i][j] = (float4v){0.f,0.f,0.f,0.f};

  // prefetch registers
  short8 pa0 = {0,0,0,0,0,0,0,0}, pa1 = {0,0,0,0,0,0,0,0};
  short4v praw[4];
  #pragma unroll
  for (int i = 0; i < 4; i++) praw[i] = (short4v){0,0,0,0};

  auto ldA = [&](int kb){
    if (aval){
      pa0 = *(const short8*)(Aptr + kb);
      pa1 = *(const short8*)(Aptr + kb + 8);
    }
  };
  auto ldB = [&](int kb){
    #pragma unroll
    for (int i = 0; i < 4; i++){
      const int k = kb + kg*4 + i;
      const unsigned short* bp = bbase + (long)k*kstep;
      if (vec4) praw[i] = *(const short4v*)bp;
      else {
        short4v u = {0,0,0,0};
        #pragma unroll
        for (int j = 0; j < 4; j++) if (lv[j]) u[j] = (short)bp[j];
        praw[i] = u;
      }
    }
  };

  ldA(0);
  if (BMODE == 0) ldB(0);

  for (int k0 = 0; k0 < g.K; k0 += 32){
    short8 sa0 = pa0, sa1 = pa1;
    short4v bpk[4];
    if (BMODE == 0){
      #pragma unroll
      for (int j = 0; j < 4; j++){
        short4v p;
        #pragma unroll
        for (int i = 0; i < 4; i++) p[i] = praw[i][j];
        bpk[j] = p;
      }
    } else { // BMODE == 2
      float tv[4][4];
      #pragma unroll
      for (int i = 0; i < 4; i++){
        const int k = k0 + kg*4 + i;
        const float pwk = g.pw[k], pbk = g.pb[k];
        #pragma unroll
        for (int j = 0; j < 4; j++) tv[i][j] = lv[j] ? silu_g((aud4[j]*pwk + pbk)*invn4[j]) : 0.f;
      }
      #pragma unroll
      for (int j = 0; j < 4; j++){
        short4v p;
        #pragma unroll
        for (int i = 0; i < 4; i++) p[i] = f2bf(tv[i][j]);
        bpk[j] = p;
      }
    }
    if (k0 + 32 < g.K){
      ldA(k0 + 32);
      if (BMODE == 0) ldB(k0 + 32);
    }

    __syncthreads();
    *(short8*)&Asm[ar*40 + ah*16]     = sa0;
    *(short8*)&Asm[ar*40 + ah*16 + 8] = sa1;
    #pragma unroll
    for (int j = 0; j < 4; j++)
      *(short4v*)&Bsm[(mg*4 + j)*40 + kg*4] = bpk[j];
    __syncthreads();

    short8 afr[4], bfr[4];
    #pragma unroll
    for (int i = 0; i < 4; i++) afr[i] = *(const short8*)&Asm[(wc*64 + i*16 + r16)*40 + q*8];
    #pragma unroll
    for (int j = 0; j < 4; j++) bfr[j] = *(const short8*)&Bsm[(wsd*64 + j*16 + r16)*40 + q*8];
    #pragma unroll
    for (int i = 0; i < 4; i++)
      #pragma unroll
      for (int j = 0; j < 4; j++)
        acc[i][j] = __builtin_amdgcn_mfma_f32_16x16x32_bf16(afr[i], bfr[j], acc[i][j], 0, 0, 0);
  }

  // ---- LDS-transpose epilogue: quarters of 32 n-rows, coalesced short8 stores ----
  {
    float* Csm = (float*)SMEMraw;   // [32][132]
    #pragma unroll
    for (int qtr = 0; qtr < 4; qtr++){
      __syncthreads();
      if (wc == (qtr >> 1)){
        #pragma unroll
        for (int ii = 0; ii < 2; ii++){
          int i = (qtr & 1)*2 + ii;
          #pragma unroll
          for (int j = 0; j < 4; j++){
            int m = wsd*64 + j*16 + r16;
            #pragma unroll
            for (int rg = 0; rg < 4; rg++)
              Csm[(ii*16 + q*4 + rg)*132 + m] = acc[i][j][rg];
          }
        }
      }
      __syncthreads();
      #pragma unroll
      for (int sp = 0; sp < 2; sp++){
        int nrow = (t >> 4) + sp*16;
        int n = n0 + qtr*32 + nrow;
        int m8 = (t & 15)*8;
        if (n >= g.N) continue;
        int sg = s0 + m8;
        int b2 = sg / FL; int r2 = sg - b2*FL;
        if (b2 >= 2) continue;
        int f2 = (g.Fdim > 1) ? (r2 / g.Lw) : 0;
        int l2 = g.lq0 + (r2 - f2*g.Lw);
        float4v v0 = *(const float4v*)&Csm[nrow*132 + m8];
        float4v v1 = *(const float4v*)&Csm[nrow*132 + m8 + 4];
        long obase = ((long)(b2*g.Nsto + n)*g.Fdim + f2)*g.CLw + (l2 - g.Cl0);
        short8 o;
        if (EMODE == 1){
          #pragma unroll
          for (int e = 0; e < 4; e++){ o[e] = f2bf(v0[e]); o[e+4] = f2bf(v1[e]); }
        } else if (EMODE == 2){
          short8 axv = *(const short8*)&g.auxXH[((long)(b2*g.N + n)*g.Fdim + f2)*2048 + l2];
          const float* ivp = &g.invn[(b2*g.Fdim + f2)*2048 + l2];
          float4v iv0 = *(const float4v*)ivp;
          float4v iv1 = *(const float4v*)(ivp + 4);
          #pragma unroll
          for (int e = 0; e < 4; e++){
            float xn0 = bf2f((unsigned short)axv[e]) * iv0[e];
            float xn1 = bf2f((unsigned short)axv[e+4]) * iv1[e];
            o[e]   = f2bf((xn0*0.7f + v0[e]*0.3f)*MPS);
            o[e+4] = f2bf((xn1*0.7f + v1[e]*0.3f)*MPS);
          }
        } else { // EMODE == 3
          float pwn = g.pw[n], pbn = g.pb[n];
          const float* ap  = &g.audio[(b2*128 + f2)*2048 + l2];
          const float* ivp = &g.invn[(b2*g.Fdim + f2)*2048 + l2];
          float4v a0 = *(const float4v*)ap,  a1 = *(const float4v*)(ap + 4);
          float4v iv0 = *(const float4v*)ivp, iv1 = *(const float4v*)(ivp + 4);
          #pragma unroll
          for (int e = 0; e < 4; e++){
            float xn0 = (a0[e]*pwn + pbn)*iv0[e];
            float xn1 = (a1[e]*pwn + pbn)*iv1[e];
            o[e]   = f2bf((xn0*0.7f + v0[e]*0.3f)*MPS);
            o[e+4] = f2bf((xn1*0.7f + v1[e]*0.3f)*MPS);
          }
        }
        *(short8*)&g.CoutH[obase] = o;
      }
    }
  }
}

// ---------------- downsample conv GEMM: 64x64 tile on pooled P, prefetched ----------------
// EMODE 0: f32 store full-L ; EMODE 1: bf16 store full-L
// LDS-transpose epilogue for coalesced stores.
struct DnArgs {
  const unsigned short* A; const unsigned short* P;
  float* Cout; unsigned short* CoutH;
  int N, K, F2, Lc, l0;
};

template<int EMODE>
__global__ __launch_bounds__(256,4) void mgemm64_kernel(DnArgs g){
  __shared__ __align__(16) char SMEM[10240];
  unsigned short* Asm = (unsigned short*)SMEM;       // [64*40]
  unsigned short* Bsm = Asm + 64*40;
  const int t = threadIdx.x;
  const int lane = t & 63;
  const int wave = t >> 6;
  const int wc = wave >> 1, wsd = wave & 1;
  const int q = lane >> 4, r16 = lane & 15;
  const int s0 = blockIdx.x * 64;
  const int n0 = blockIdx.y * 64;
  const int FL = g.F2 * g.Lc;

  const int ar = t >> 2, ah = t & 3;
  const unsigned short* Aptr = g.A + (long)(n0 + ar)*g.K + ah*8;
  const int kg = t & 7, mg = t >> 3;
  const bool bstage = (mg < 16);
  const int mb = s0 + (mg & 15)*4;
  const int bcol = mb / FL; const int rr = mb - bcol*FL;
  const int fcol = rr / g.Lc; const int li = rr - fcol*g.Lc;
  const unsigned short* bbase = g.P + ((long)(bcol*g.K)*g.F2 + fcol)*g.Lc + li;
  const long kstep = (long)g.F2 * g.Lc;

  float4v acc[2][2];
  #pragma unroll
  for (int i = 0; i < 2; i++)
    #pragma unroll
    for (int j = 0; j < 2; j++) acc[i][j] = (float4v){0.f,0.f,0.f,0.f};

  short8 pa = {0,0,0,0,0,0,0,0};
  short4v praw[4];
  #pragma unroll
  for (int i = 0; i < 4; i++) praw[i] = (short4v){0,0,0,0};

  auto ldA = [&](int kb){ pa = *(const short8*)(Aptr + kb); };
  auto ldB = [&](int kb){
    if (bstage){
      #pragma unroll
      for (int i = 0; i < 4; i++)
        praw[i] = *(const short4v*)(bbase + (long)(kb + kg*4 + i)*kstep);
    }
  };
  ldA(0); ldB(0);

  for (int k0 = 0; k0 < g.K; k0 += 32){
    short8 sa = pa;
    short4v bpk[4];
    #pragma unroll
    for (int j = 0; j < 4; j++){
      short4v p;
      #pragma unroll
      for (int i = 0; i < 4; i++) p[i] = praw[i][j];
      bpk[j] = p;
    }
    if (k0 + 32 < g.K){ ldA(k0 + 32); ldB(k0 + 32); }

    __syncthreads();
    *(short8*)&Asm[ar*40 + ah*8] = sa;
    if (bstage){
      #pragma unroll
      for (int j = 0; j < 4; j++)
        *(short4v*)&Bsm[((mg & 15)*4 + j)*40 + kg*4] = bpk[j];
    }
    __syncthreads();

    short8 afr[2], bfr[2];
    #pragma unroll
    for (int i = 0; i < 2; i++) afr[i] = *(const short8*)&Asm[(wc*32 + i*16 + r16)*40 + q*8];
    #pragma unroll
    for (int j = 0; j < 2; j++) bfr[j] = *(const short8*)&Bsm[(wsd*32 + j*16 + r16)*40 + q*8];
    #pragma unroll
    for (int i = 0; i < 2; i++)
      #pragma unroll
      for (int j = 0; j < 2; j++)
        acc[i][j] = __builtin_amdgcn_mfma_f32_16x16x32_bf16(afr[i], bfr[j], acc[i][j], 0, 0, 0);
  }

  // ---- LDS-transpose epilogue: quarters of 16 n-rows ----
  {
    float* Csm = (float*)SMEM;   // [16][68]
    const int b2 = s0 / FL; const int r20 = s0 - b2*FL;
    const int f2c = r20 / g.Lc; const int l2c = g.l0 + (r20 - f2c*g.Lc);
    #pragma unroll
    for (int nq = 0; nq < 4; nq++){
      __syncthreads();
      if (wc == (nq >> 1)){
        const int i = nq & 1;
        #pragma unroll
        for (int j = 0; j < 2; j++)
          #pragma unroll
          for (int rg = 0; rg < 4; rg++)
            Csm[(q*4 + rg)*68 + wsd*32 + j*16 + r16] = acc[i][j][rg];
      }
      __syncthreads();
      int nrow = t >> 4;
      int mq = (t & 15)*4;
      int n = n0 + nq*16 + nrow;
      float4v v = *(const float4v*)&Csm[nrow*68 + mq];
      long oidx = ((long)(b2*g.N + n)*g.F2 + f2c)*2048 + l2c + mq;
      if (EMODE == 0){
        *(float4v*)&g.Cout[oidx] = v;
      } else {
        short4v o = { f2bf(v[0]), f2bf(v[1]), f2bf(v[2]), f2bf(v[3]) };
        *(short4v*)&g.CoutH[oidx] = o;
      }
    }
  }
}

// ---------------- seq out GEMM: 64x64 tile, Fdim=1, prefetched ----------------
// EMODE 5: mp_add -> f32 Cout ; EMODE 6: mp_add + silu -> f32 Cout
// LDS-transpose epilogue for coalesced f32x4 stores + vector aux/invn reads.
template<int EMODE>
__global__ __launch_bounds__(256,4) void seqout_kernel(const unsigned short* __restrict__ A,
                                                       const unsigned short* __restrict__ Bh,
                                                       const float* __restrict__ invn,
                                                       const float* __restrict__ auxX,
                                                       float* __restrict__ Cout, int K){
  __shared__ __align__(16) char SMEM[10240];
  unsigned short* Asm = (unsigned short*)SMEM;       // [64*40]
  unsigned short* Bsm = Asm + 64*40;
  const int t = threadIdx.x;
  const int lane = t & 63;
  const int wave = t >> 6;
  const int wc = wave >> 1, wsd = wave & 1;
  const int q = lane >> 4, r16 = lane & 15;
  const int s0 = blockIdx.x * 64;
  const int n0 = blockIdx.y * 64;

  const int ar = t >> 2, ah = t & 3;
  const unsigned short* Aptr = A + (long)(n0 + ar)*K + ah*8;
  const int kg = t & 7, mg = t >> 3;
  const bool bstage = (mg < 16);
  const int mb = s0 + (mg & 15)*4;
  const int bcol = mb >> 11, lb = mb & 2047;
  const unsigned short* bbase = Bh + ((long)bcol*K)*2048 + lb;

  float4v acc[2][2];
  #pragma unroll
  for (int i = 0; i < 2; i++)
    #pragma unroll
    for (int j = 0; j < 2; j++) acc[i][j] = (float4v){0.f,0.f,0.f,0.f};

  short8 pa = {0,0,0,0,0,0,0,0};
  short4v praw[4];
  #pragma unroll
  for (int i = 0; i < 4; i++) praw[i] = (short4v){0,0,0,0};

  auto ldA = [&](int kb){ pa = *(const short8*)(Aptr + kb); };
  auto ldB = [&](int kb){
    if (bstage){
      #pragma unroll
      for (int i = 0; i < 4; i++)
        praw[i] = *(const short4v*)(bbase + (long)(kb + kg*4 + i)*2048);
    }
  };
  ldA(0); ldB(0);

  for (int k0 = 0; k0 < K; k0 += 32){
    short8 sa = pa;
    short4v bpk[4];
    #pragma unroll
    for (int j = 0; j < 4; j++){
      short4v p;
      #pragma unroll
      for (int i = 0; i < 4; i++) p[i] = praw[i][j];
      bpk[j] = p;
    }
    if (k0 + 32 < K){ ldA(k0 + 32); ldB(k0 + 32); }

    __syncthreads();
    *(short8*)&Asm[ar*40 + ah*8] = sa;
    if (bstage){
      #pragma unroll
      for (int j = 0; j < 4; j++)
        *(short4v*)&Bsm[((mg & 15)*4 + j)*40 + kg*4] = bpk[j];
    }
    __syncthreads();

    short8 afr[2], bfr[2];
    #pragma unroll
    for (int i = 0; i < 2; i++) afr[i] = *(const short8*)&Asm[(wc*32 + i*16 + r16)*40 + q*8];
    #pragma unroll
    for (int j = 0; j < 2; j++) bfr[j] = *(const short8*)&Bsm[(wsd*32 + j*16 + r16)*40 + q*8];
    #pragma unroll
    for (int i = 0; i < 2; i++)
      #pragma unroll
      for (int j = 0; j < 2; j++)
        acc[i][j] = __builtin_amdgcn_mfma_f32_16x16x32_bf16(afr[i], bfr[j], acc[i][j], 0, 0, 0);
  }

  // ---- LDS-transpose epilogue ----
  {
    float* Csm = (float*)SMEM;   // [16][68]
    const int b2 = s0 >> 11; const int l0b = s0 & 2047;
    #pragma unroll
    for (int nq = 0; nq < 4; nq++){
      __syncthreads();
      if (wc == (nq >> 1)){
        const int i = nq & 1;
        #pragma unroll
        for (int j = 0; j < 2; j++)
          #pragma unroll
          for (int rg = 0; rg < 4; rg++)
            Csm[(q*4 + rg)*68 + wsd*32 + j*16 + r16] = acc[i][j][rg];
      }
      __syncthreads();
      int nrow = t >> 4;
      int mq = (t & 15)*4;
      int n = n0 + nq*16 + nrow;
      int l = l0b + mq;
      float4v v = *(const float4v*)&Csm[nrow*68 + mq];
      float4v ax = *(const float4v*)&auxX[((long)b2*512 + n)*2048 + l];
      float4v iv = *(const float4v*)&invn[b2*2048 + l];
      float4v r;
      #pragma unroll
      for (int e = 0; e < 4; e++){
        float xn = ax[e]*iv[e];
        float rr = (xn*0.7f + v[e]*0.3f)*MPS;
        r[e] = (EMODE == 6) ? silu_g(rr) : rr;
      }
      *(float4v*)&Cout[((long)b2*512 + n)*2048 + l] = r;
    }
  }
}

// ---------------- freq-pool: P[b,k,f2,l] = mean_p Hb[b,k,f2*s+p,l], bf16 ----------------
__global__ __launch_bounds__(256) void poolf_kernel(const unsigned short* __restrict__ Hb,
                                                    unsigned short* __restrict__ P,
                                                    int F2, int s, int Lc, long total4){
  long i = blockIdx.x*256 + threadIdx.x;
  if (i >= total4) return;
  long e = i*4;
  int li = (int)(e % Lc); long r0 = e / Lc;
  int f2 = (int)(r0 % F2); long r = r0 / F2;        // r = b*Kc + k
  const unsigned short* src = Hb + ((long)r*F2*s + (long)f2*s)*Lc + li;
  float a0=0,a1=0,a2=0,a3=0;
  for (int p = 0; p < s; p++){
    short4v u = *(const short4v*)(src + (long)p*Lc);
    a0 += bf2f((unsigned short)u[0]); a1 += bf2f((unsigned short)u[1]);
    a2 += bf2f((unsigned short)u[2]); a3 += bf2f((unsigned short)u[3]);
  }
  float inv = 1.f/(float)s;
  short4v o = { f2bf(a0*inv), f2bf(a1*inv), f2bf(a2*inv), f2bf(a3*inv) };
  *(short4v*)&P[((long)r*F2 + f2)*Lc + li] = o;
}

// ---------------- depthwise 5x3 conv (+ silu), bf16 in/out ----------------
// 8 f-rows x 8 l per thread: 12 row-loads per 8 outputs (halo amplification 1.5x vs 2x)
struct DwArgs { const unsigned short* R1; const unsigned short* wd; unsigned short* R2; int C, F, Lc, l0; };
__global__ __launch_bounds__(256) void dw2d_kernel(DwArgs a){
  int idx = blockIdx.x*256 + threadIdx.x;
  int Lq = a.Lc >> 3;
  int Fq = a.F >> 3;
  int total = 2*a.C*Fq*Lq;
  if (idx >= total) return;
  int lq = idx % Lq; int r = idx / Lq;
  int fq = r % Fq; r /= Fq;
  int c = r % a.C; int b = r / a.C;
  int f0 = fq*8;
  int labs = a.l0 + lq*8;
  int Lw = a.Lc + 8;
  const unsigned short* base = a.R1 + (long)((b*a.C + c)*a.F)*Lw + (labs - (a.l0 - 4));
  const unsigned short* w = a.wd + c*15;
  float W[5][3];
  #pragma unroll
  for (int tp = 0; tp < 5; tp++)
    #pragma unroll
    for (int j = 0; j < 3; j++) W[tp][j] = bf2f(w[tp*3 + j]);

  const bool llo = (labs > 0);
  const bool lhi = (labs + 8 < 2048);
  float acc[8][8];
  #pragma unroll
  for (int t = 0; t < 8; t++)
    #pragma unroll
    for (int j = 0; j < 8; j++) acc[t][j] = 0.f;

  #pragma unroll
  for (int r12 = 0; r12 < 12; r12++){
    int rrow = f0 - 2 + r12;
    if (rrow < 0 || rrow >= a.F) continue;
    const unsigned short* p = base + (long)rrow*Lw;
    short4v u0 = *(const short4v*)p;
    short4v u1 = *(const short4v*)(p + 4);
    float x[10];
    x[0] = llo ? bf2f(p[-1]) : 0.f;
    x[1] = bf2f((unsigned short)u0[0]); x[2] = bf2f((unsigned short)u0[1]);
    x[3] = bf2f((unsigned short)u0[2]); x[4] = bf2f((unsigned short)u0[3]);
    x[5] = bf2f((unsigned short)u1[0]); x[6] = bf2f((unsigned short)u1[1]);
    x[7] = bf2f((unsigned short)u1[2]); x[8] = bf2f((unsigned short)u1[3]);
    x[9] = lhi ? bf2f(p[8]) : 0.f;
    #pragma unroll
    for (int t = 0; t < 8; t++){
      const int df = r12 - 2 - t;          // compile-time per (r12,t)
      if (df < -2 || df > 2) continue;
      float w0 = W[df+2][0], w1 = W[df+2][1], w2 = W[df+2][2];
      #pragma unroll
      for (int j = 0; j < 8; j++)
        acc[t][j] += w0*x[j] + w1*x[j+1] + w2*x[j+2];
    }
  }

  unsigned short* ob = a.R2 + ((long)((b*a.C + c)*a.F + f0))*a.Lc + (labs - a.l0);
  #pragma unroll
  for (int t = 0; t < 8; t++){
    short8 o;
    #pragma unroll
    for (int j = 0; j < 8; j++) o[j] = f2bf(silu_g(acc[t][j]));
    *(short8*)(ob + (long)t*a.Lc) = o;
  }
}

// ---------------- seq depthwise 3-tap (+ silu), transposed layouts ----------------
__global__ __launch_bounds__(256) void dwseqT_kernel(const unsigned short* __restrict__ HST,
                                                     const unsigned short* __restrict__ w,
                                                     unsigned short* __restrict__ H2T){
  int idx = blockIdx.x*256 + threadIdx.x;
  if (idx >= 2*2048*128) return;
  int c0 = (idx & 127) * 8; long bt = idx >> 7;     // bt = b*2048 + t
  int tt = (int)(bt & 2047);
  const unsigned short* base = HST + bt*1024 + c0;
  short8 zz = {0,0,0,0,0,0,0,0};
  short8 x1 = *(const short8*)base;
  short8 x0 = (tt > 0)    ? *(const short8*)(base - 1024) : zz;
  short8 x2 = (tt < 2047) ? *(const short8*)(base + 1024) : zz;
  const unsigned short* wp = w + c0*3;
  short8 o;
  #pragma unroll
  for (int j = 0; j < 8; j++){
    float w0 = bf2f(wp[3*j]), w1 = bf2f(wp[3*j+1]), w2 = bf2f(wp[3*j+2]);
    float v = w0*bf2f((unsigned short)x0[j]) + w1*bf2f((unsigned short)x1[j]) + w2*bf2f((unsigned short)x2[j]);
    o[j] = f2bf(silu_g(v));
  }
  *(short8*)&H2T[bt*1024 + c0] = o;
}

// ---------------- minGRU scan + gate (bf16 z/c) ----------------
__global__ __launch_bounds__(256) void scan_kernel(const unsigned short* __restrict__ ZC, const unsigned short* __restrict__ G,
                                                   unsigned short* __restrict__ SC){
  int bc = blockIdx.x;            // 0..2047 = b*1024+c
  int b = bc >> 10, c = bc & 1023;
  const unsigned short* zrow = ZC + ((long)(b*2048 + c))*2048;
  const unsigned short* crow = ZC + ((long)(b*2048 + 1024 + c))*2048;
  const unsigned short* grow = G + (long)bc*2048;
  unsigned short* orow = SC + (long)bc*2048;
  int tid = threadIdx.x;
  int t0 = tid*8;
  short8 zv = *(const short8*)&zrow[t0];
  short8 cv = *(const short8*)&crow[t0];
  float av[8], bv[8];
  float A = 1.f, Bv = 0.f;
  #pragma unroll
  for (int j = 0; j < 8; j++){
    float z = bf2f((unsigned short)zv[j]); float cval = bf2f((unsigned short)cv[j]);
    float zs = 1.f/(1.f + __expf(-z));
    float a = 1.f - zs; float bb = zs*cval;
    av[j] = a; bv[j] = bb;
    Bv = a*Bv + bb;
    A = a*A;
  }
  __shared__ float sA[256], sB[256];
  sA[tid] = A; sB[tid] = Bv;
  __syncthreads();
  for (int off = 1; off < 256; off <<= 1){
    float pA = 1.f, pB = 0.f;
    if (tid >= off){ pA = sA[tid-off]; pB = sB[tid-off]; }
    __syncthreads();
    float nA = A*pA; float nB = A*pB + Bv;
    A = nA; Bv = nB;
    sA[tid] = A; sB[tid] = Bv;
    __syncthreads();
  }
  float h = (tid > 0) ? sB[tid-1] : 0.f;
  short8 gv = *(const short8*)&grow[t0];
  short8 ov;
  #pragma unroll
  for (int j = 0; j < 8; j++){
    h = av[j]*h + bv[j];
    ov[j] = f2bf(h * silu_g(bf2f((unsigned short)gv[j])));
  }
  *(short8*)&orow[t0] = ov;
}

extern "C" void kernel_launch(void* const* d_in, const int* in_sizes, int n_in,
                              void* d_out, int out_size, void* d_ws, size_t ws_size,
                              hipStream_t stream) {
  const float* audio = (const float*)d_in[0];
  const float* pw = (const float*)d_in[1];
  const float* pb = (const float*)d_in[2];
  const float* cw1[3] = {(const float*)d_in[3], (const float*)d_in[7], (const float*)d_in[11]};
  const float* cwd[3] = {(const float*)d_in[4], (const float*)d_in[8], (const float*)d_in[12]};
  const float* cw2[3] = {(const float*)d_in[5], (const float*)d_in[9], (const float*)d_in[13]};
  const float* cdn[3] = {(const float*)d_in[6], (const float*)d_in[10], (const float*)d_in[14]};
  const float* hgw  = (const float*)d_in[15];
  const float* dww  = (const float*)d_in[16];
  const float* gruw = (const float*)d_in[17];
  const float* outw = (const float*)d_in[18];
  float* out = (float*)d_out;

  // ---- workspace layout (bytes) ----
  char* P0 = (char*)d_ws;
  float*          INVW = (float*)P0;                    P0 += 131072;     // S at [32000]
  unsigned short* WBF  = (unsigned short*)P0;           P0 += 30443776;   // 15,221,888 bf16
  float*          INVN = (float*)P0;                    P0 += 2097152;
  char*           XBZC = P0;                            P0 += 33554432;   // XB (conv b1/b2) / ZC bf16 (seq)
  unsigned short* IN1h = (unsigned short*)P0;           P0 += 33554432;   // b0 out bf16; seq scratch later
  unsigned short* IN2h = (unsigned short*)P0;           P0 += 16777216;   // b1 out bf16
  float*          SEQ  = (float*)P0;                    P0 += 8388608;    // b2 out fp32
  char*           ARENA = P0;
  long arenaBytes = (long)ws_size - (long)(P0 - (char*)d_ws);
  float* S = INVW + 32000;

  // weight table (order: cw1/cwd/cw2/cdn x3, hg, dww, gru, out)
  const float* wsrc[16] = {cw1[0],cwd[0],cw2[0],cdn[0], cw1[1],cwd[1],cw2[1],cdn[1],
                           cw1[2],cwd[2],cw2[2],cdn[2], hgw, dww, gruw, outw};
  int Os[16] = {128,128,64,128, 256,256,128,256, 512,512,256,512, 8192,4096,8192,2048};
  int Ks[16] = {64,15,128,64, 128,15,256,128, 256,15,512,256, 512,3,1024,1024};
  int wbfOff[16];
  {
    int wo = 0;
    for (int i = 0; i < 16; i++){ wbfOff[i] = wo; wo += Os[i]*Ks[i]; }
  }
  {
    NcArgs na;
    int rows = 0;
    for (int i = 0; i < 16; i++){
      na.e[i].w = wsrc[i]; na.e[i].O = Os[i]; na.e[i].K = Ks[i]; na.e[i].dstOff = wbfOff[i];
      rows += Os[i];
    }
    normcast_kernel<<<rows, 64, 0, stream>>>(na, WBF);
  }
  projstats_kernel<<<1, 64, 0, stream>>>(pw, pb, S);

  // ---- conv blocks ----
  int Cin_[3]  = {64,128,256};
  int Cmid_[3] = {128,256,512};
  int F_[3]    = {128,32,8};
  int s_[3]    = {4,4,8};
  const unsigned short* XinH[3] = {nullptr, IN1h, IN2h};
  unsigned short* XoutH[3] = {IN1h, IN2h, nullptr};
  int iW1[3]={0,4,8}, iWd[3]={1,5,9}, iW2[3]={2,6,10}, iDn[3]={3,7,11};

  for (int b = 0; b < 3; b++){
    int Cin = Cin_[b], Cmid = Cmid_[b], F = F_[b], s = s_[b];
    int F2 = F/s;
    int nc = 16;
    for (int c = 1; c <= 16; c <<= 1){
      long Lc = 2048/c;
      long bytes = 2L*(2L*Cmid*F*(Lc+8) + 2L*Cmid*F*Lc + 2L*Cin*F*Lc + 2L*Cin*F2*Lc);
      if (bytes <= arenaBytes){ nc = c; break; }
    }
    int Lc = 2048/nc;
    unsigned short* R1 = (unsigned short*)ARENA;
    unsigned short* R2 = R1 + 2L*Cmid*F*(Lc+8);
    unsigned short* Hb = R2 + 2L*Cmid*F*Lc;
    unsigned short* Pb = Hb + 2L*Cin*F*Lc;
    unsigned short* XB = (unsigned short*)XBZC;

    if (b == 0){
      invn_audio_kernel<<<(2*128*2048/4+255)/256, 256, 0, stream>>>(audio, S, INVN);
    } else {
      int positions = 2*F*2048;
      invn_reduce_kernel<8,true><<<positions/32, 256, 0, stream>>>(XinH[b], INVN, Cin, F);
      long total4 = (long)2*Cin*F*2048/4;
      applynorm_kernel<true,true><<<(int)((total4+255)/256), 256, 0, stream>>>(XinH[b], INVN, XB, Cin, F, total4);
    }

    for (int ci = 0; ci < nc; ci++){
      int l0 = ci*Lc;
      // conv1: Cin -> Cmid on window [l0-4, l0+Lc+4) -> R1 bf16
      GemmArgs ga{};
      ga.A = WBF + wbfOff[iW1[b]];
      ga.Bh = XB; ga.invn = INVN; ga.audio = audio; ga.pw = pw; ga.pb = pb;
      ga.CoutH = R1; ga.N = Cmid; ga.K = Cin; ga.Fdim = F; ga.Lw = Lc+8; ga.lq0 = l0-4;
      ga.BLw = 2048; ga.Bl0 = 0; ga.CLw = Lc+8; ga.Cl0 = l0-4; ga.Nsto = Cmid; ga.Fsrc = F;
      int M1 = 2*F*(Lc+8);
      dim3 g1((M1+127)/128, (Cmid+127)/128);
      if (b == 0) mgemm_kernel<2,1><<<g1,256,0,stream>>>(ga);
      else        mgemm_kernel<0,1><<<g1,256,0,stream>>>(ga);
      // depthwise 5x3 + silu -> R2 bf16 (8f x 8l per thread)
      DwArgs da{R1, WBF + wbfOff[iWd[b]], R2, Cmid, F, Lc, l0};
      int tdw = 2*Cmid*(F/8)*(Lc/8);
      dw2d_kernel<<<(tdw+255)/256, 256, 0, stream>>>(da);
      // conv2 + mp_add -> Hb bf16
      GemmArgs gb{};
      gb.A = WBF + wbfOff[iW2[b]];
      gb.Bh = R2; gb.invn = INVN; gb.audio = audio; gb.pw = pw; gb.pb = pb; gb.auxXH = XinH[b];
      gb.CoutH = Hb; gb.N = Cin; gb.K = Cmid; gb.Fdim = F; gb.Lw = Lc; gb.lq0 = l0;
      gb.BLw = Lc; gb.Bl0 = l0; gb.CLw = Lc; gb.Cl0 = l0; gb.Nsto = Cin; gb.Fsrc = F;
      int M2 = 2*F*Lc;
      dim3 g2((M2+127)/128, (Cin+127)/128);
      if (b == 0) mgemm_kernel<0,3><<<g2,256,0,stream>>>(gb);
      else        mgemm_kernel<0,2><<<g2,256,0,stream>>>(gb);
      // freq-pool Hb -> Pb (bf16)
      long tp4 = (2L*Cin*F2*Lc)/4;
      poolf_kernel<<<(int)((tp4+255)/256), 256, 0, stream>>>(Hb, Pb, F2, s, Lc, tp4);
      // dn conv on pooled P -> Xout (bf16 full-L for b0/b1; fp32 SEQ for b2)
      DnArgs dn{};
      dn.A = WBF + wbfOff[iDn[b]]; dn.P = Pb;
      dn.Cout = SEQ; dn.CoutH = XoutH[b];
      dn.N = Cmid; dn.K = Cin; dn.F2 = F2; dn.Lc = Lc; dn.l0 = l0;
      dim3 gdn((2*F2*Lc)/64, Cmid/64);
      if (b == 2) mgemm64_kernel<0><<<gdn,256,0,stream>>>(dn);
      else        mgemm64_kernel<1><<<gdn,256,0,stream>>>(dn);
    }
  }

  // ---- seq blocks: K-major transposed activations (XST/HST/H2T), gemmT for hg & gru ----
  unsigned short* XST = IN1h;                 // [b][2048][512]  bf16
  unsigned short* HST = XST + 2097152;        // [b][2048][1024] bf16
  unsigned short* G   = HST + 4194304;        // [b][1024][2048] bf16
  unsigned short* H2T = G  + 4194304;         // [b][2048][1024] bf16
  unsigned short* SC  = H2T + 4194304;        // [b*1024+c][2048] bf16
  unsigned short* ZCh = (unsigned short*)XBZC;

  for (int i = 0; i < 4; i++){
    invn_reduce_kernel<16,false><<<4096/16, 256, 0, stream>>>(SEQ, INVN, 512, 1);
    normT_kernel<<<dim3(32,8,2), 256, 0, stream>>>(SEQ, INVN, XST);
    // hg conv: N=2048, K=512 ; h half -> silu -> HST (transposed), g half -> G
    GTArgs gh{ WBF + wbfOff[12] + (long)i*2048*512, XST, HST, G, 2048, 512 };
    gemmT_kernel<1><<<dim3(32,16), 256, 0, stream>>>(gh);
    // depthwise 3-tap + silu (transposed in/out)
    dwseqT_kernel<<<2048, 256, 0, stream>>>(HST, WBF + wbfOff[13] + i*1024*3, H2T);
    // gru conv 1024 -> 2048 (z|c) -> ZCh bf16 ([b][2048][l] for scan)
    GTArgs gz{ WBF + wbfOff[14] + (long)i*2048*1024, H2T, ZCh, nullptr, 2048, 1024 };
    gemmT_kernel<0><<<dim3(32,16), 256, 0, stream>>>(gz);
    // scan + gate -> SC bf16
    scan_kernel<<<2048,256,0,stream>>>(ZCh, G, SC);
    // out conv + mp_add -> SEQ (i<3) or mp_add+silu -> d_out (i==3)
    const unsigned short* oA = WBF + wbfOff[15] + (long)i*512*1024;
    if (i < 3) seqout_kernel<5><<<dim3(64,8),256,0,stream>>>(oA, SC, INVN, SEQ, SEQ, 1024);
    else       seqout_kernel<6><<<dim3(64,8),256,0,stream>>>(oA, SC, INVN, SEQ, out, 1024);
  }

  (void)in_sizes; (void)n_in; (void)out_size;
}

// Round 6
// 1107.308 us; speedup vs baseline: 1.0981x; 1.0981x over previous
//
#include <hip/hip_runtime.h>
#include <math.h>

#define GAIN 1.6778523489932886f     // 1/0.596
#define MPS  1.3130643285972254f     // 1/sqrt(0.7^2+0.3^2)

typedef __attribute__((ext_vector_type(8))) short short8;
typedef __attribute__((ext_vector_type(4))) short short4v;
typedef __attribute__((ext_vector_type(4))) float float4v;

__device__ __forceinline__ float silu_g(float x){
  float s = 1.0f/(1.0f + __expf(-x));
  return x*s*GAIN;
}
__device__ __forceinline__ short f2bf(float f){
  unsigned u = __builtin_bit_cast(unsigned, f);
  u += 0x7fffu + ((u >> 16) & 1u);
  return (short)(u >> 16);
}
__device__ __forceinline__ float bf2f(unsigned short h){
  return __builtin_bit_cast(float, ((unsigned)h) << 16);
}

// async global->LDS, 16B per lane (dest is wave-uniform base + lane*16)
typedef __attribute__((address_space(3))) unsigned int as3_uint;
typedef const __attribute__((address_space(1))) unsigned int as1_cuint;
__device__ __forceinline__ void gload16(const unsigned short* gsrc, unsigned short* ldst){
  __builtin_amdgcn_global_load_lds((as1_cuint*)gsrc, (as3_uint*)ldst, 16, 0, 0);
}

// ---------------- fused weight row-norm + bf16 cast (one wave per row) ----------------
struct NcEnt { const float* w; int O, K, dstOff; };
struct NcArgs { NcEnt e[16]; };

__global__ __launch_bounds__(64) void normcast_kernel(NcArgs na, unsigned short* __restrict__ wbf){
  int row = blockIdx.x;
  int base = 0; int i;
  for (i = 0; i < 16; i++){
    if (row < base + na.e[i].O) break;
    base += na.e[i].O;
  }
  if (i >= 16) return;
  int r = row - base; int K = na.e[i].K;
  const float* w = na.e[i].w + (long)r*K;
  unsigned short* dst = wbf + na.e[i].dstOff + (long)r*K;
  int tid = threadIdx.x;
  float s = 0.f;
  const bool v4 = ((K & 3) == 0);
  if (v4){
    for (int k = tid*4; k < K; k += 256){
      float4v v = *(const float4v*)&w[k];
      s += v[0]*v[0] + v[1]*v[1] + v[2]*v[2] + v[3]*v[3];
    }
  } else {
    for (int k = tid; k < K; k += 64){ float v = w[k]; s += v*v; }
  }
  for (int off = 32; off; off >>= 1) s += __shfl_down(s, off);
  float inv = rsqrtf(__shfl(s, 0) + 1e-8f);
  if (v4){
    for (int k = tid*4; k < K; k += 256){
      float4v v = *(const float4v*)&w[k];
      short4v o = { f2bf(v[0]*inv), f2bf(v[1]*inv), f2bf(v[2]*inv), f2bf(v[3]*inv) };
      *(short4v*)&dst[k] = o;
    }
  } else {
    for (int k = tid; k < K; k += 64) dst[k] = (unsigned short)f2bf(w[k]*inv);
  }
}

// ---------------- audio projection stats (one wave) ----------------
__global__ __launch_bounds__(64) void projstats_kernel(const float* __restrict__ pw, const float* __restrict__ pb,
                                                       float* __restrict__ S){
  int t = threadIdx.x;
  float p = pw[t], q = pb[t];
  float s1 = p*p, s2 = p*q, s3 = q*q;
  for (int off = 32; off; off >>= 1){
    s1 += __shfl_down(s1, off); s2 += __shfl_down(s2, off); s3 += __shfl_down(s3, off);
  }
  if (t == 0){ S[0] = s1; S[1] = s2; S[2] = s3; }
}

// ---------------- b0 inverse pixel-norm (closed form, element-wise 4-wide) ----------------
__global__ __launch_bounds__(256) void invn_audio_kernel(const float* __restrict__ audio, const float* __restrict__ S,
                                                         float* __restrict__ invn){
  long i = blockIdx.x*256 + threadIdx.x;
  if (i >= (2L*128*2048)/4) return;
  long e = i*4;
  float S1 = S[0], S2 = S[1], S3 = S[2];
  float4v a = *(const float4v*)&audio[e];
  float4v o;
  #pragma unroll
  for (int j = 0; j < 4; j++) o[j] = rsqrtf((a[j]*a[j]*S1 + 2.f*a[j]*S2 + S3)/64.f + 1e-4f);
  *(float4v*)&invn[e] = o;
}

// ---------------- pixel-norm reduce (fp32 or bf16 source) ----------------
template<int G, bool BF>
__global__ __launch_bounds__(256) void invn_reduce_kernel(const void* __restrict__ Xv, float* __restrict__ invn,
                                                          int C, int F){
  constexpr int L = 256/G;
  int t = threadIdx.x; int cs = t / L; int li = t % L;
  long pos = (long)blockIdx.x*L + li;
  int bf = (int)(pos >> 11); int l = (int)(pos & 2047);
  int b = bf / F; int f = bf - b*F;
  long base = ((long)b*C*F + f)*2048 + l;
  long stride = (long)F*2048;
  float s = 0.f;
  if (BF){
    const unsigned short* X = (const unsigned short*)Xv;
    for (int c = cs; c < C; c += G){ float v = bf2f(X[base + (long)c*stride]); s += v*v; }
  } else {
    const float* X = (const float*)Xv;
    for (int c = cs; c < C; c += G){ float v = X[base + (long)c*stride]; s += v*v; }
  }
  __shared__ float red[256];
  red[t] = s; __syncthreads();
  #pragma unroll
  for (int off = G/2; off > 0; off >>= 1){
    if (cs < off) red[t] += red[t + off*L];
    __syncthreads();
  }
  if (cs == 0) invn[pos] = rsqrtf(red[li]/(float)C + 1e-4f);
}

// ---------------- pixel-norm apply (fp32 or bf16 source) ----------------
template<bool SILU, bool BF>
__global__ __launch_bounds__(256) void applynorm_kernel(const void* __restrict__ Xv, const float* __restrict__ invn,
                                                        unsigned short* __restrict__ XB, int C, int F, long total4){
  long i = blockIdx.x*256 + threadIdx.x;
  if (i >= total4) return;
  long e = i*4;
  int l = (int)(e & 2047); long r = e >> 11;      // r = (b*C + c)*F + f
  int f = (int)(r % F); long bc = r / F; int b = (int)(bc / C);
  float4v x;
  if (BF){
    short4v u = *(const short4v*)((const unsigned short*)Xv + e);
    x = (float4v){ bf2f((unsigned short)u[0]), bf2f((unsigned short)u[1]),
                   bf2f((unsigned short)u[2]), bf2f((unsigned short)u[3]) };
  } else {
    x = *(const float4v*)((const float*)Xv + e);
  }
  float4v iv = *(const float4v*)&invn[((long)b*F + f)*2048 + l];
  short4v o;
  #pragma unroll
  for (int j = 0; j < 4; j++){
    float v = x[j]*iv[j];
    o[j] = f2bf(SILU ? silu_g(v) : v);
  }
  *(short4v*)&XB[e] = o;
}

// ---------------- seq pixel-norm + transpose: SEQ f32 [b][512][l] -> XST bf16 [b][l][512] ----------------
__global__ __launch_bounds__(256) void normT_kernel(const float* __restrict__ SEQ,
                                                    const float* __restrict__ invn,
                                                    unsigned short* __restrict__ XST){
  __shared__ float tile[64][65];
  const int l0 = blockIdx.x*64, c0 = blockIdx.y*64, b = blockIdx.z;
  const int t = threadIdx.x;
  const int lr = (t & 15)*4;   // l offset within tile (float4)
  const int cr = t >> 4;       // c row, 16 per pass
  #pragma unroll
  for (int p = 0; p < 4; p++){
    int c = cr + p*16;
    float4v v = *(const float4v*)&SEQ[((long)(b*512 + c0 + c))*2048 + l0 + lr];
    tile[c][lr+0] = v[0]; tile[c][lr+1] = v[1]; tile[c][lr+2] = v[2]; tile[c][lr+3] = v[3];
  }
  __syncthreads();
  const int cc = (t & 7)*8;    // c offset within tile (8 wide)
  const int lw = t >> 3;       // l row, 32 per pass
  #pragma unroll
  for (int p = 0; p < 2; p++){
    int l = lw + p*32;
    float iv = invn[b*2048 + l0 + l];
    short8 o;
    #pragma unroll
    for (int j = 0; j < 8; j++) o[j] = f2bf(tile[cc+j][l] * iv);
    *(short8*)&XST[((long)(b*2048 + l0 + l))*512 + c0 + cc] = o;
  }
}

// ---------------- K-major fused GEMM for seq blocks ----------------
// A: [N][K] bf16 (normalized weights), B: [M][K] bf16 (M = b*2048 + l)
// EMODE 0 (gz): O1 = ZCh [b][2048][l]
// EMODE 1 (gh): n<1024 -> silu -> O1 = HST [b][l][1024] (packed), else raw -> O2 = G [b][1024][l]
// 3-buffer LDS, global_load_lds staging (pre-swizzled source + XOR-swizzled ds_read),
// counted vmcnt (8/4/0), raw s_barrier. LDS-transpose epilogue for coalesced stores.
struct GTArgs {
  const unsigned short* A;
  const unsigned short* B;
  unsigned short* O1;
  unsigned short* O2;
  int N, K;
};

template<int EMODE>
__global__ __launch_bounds__(256,2) void gemmT_kernel(GTArgs g){
  __shared__ __align__(16) char SMEMraw[49152];
  unsigned short (*Asm)[4096] = (unsigned short (*)[4096])SMEMraw;            // [3][128*32]
  unsigned short (*Bsm)[4096] = (unsigned short (*)[4096])(SMEMraw + 24576);
  const int t = threadIdx.x;
  const int lane = t & 63;
  const int wc = (t >> 7) & 1;        // N-half
  const int wsd = (t >> 6) & 1;       // M-half
  const int q = lane >> 4, r16 = lane & 15;
  const int m0 = blockIdx.x * 128;
  const int n0 = blockIdx.y * 128;
  const int K = g.K;

  const int r0 = t >> 2;
  const int c8 = (((t & 3) ^ ((r0 >> 1) & 3)) << 3);
  const unsigned short* Ap = g.A + (long)(n0 + r0)*K + c8;
  const unsigned short* Bp = g.B + (long)(m0 + r0)*K + c8;

  auto stage = [&](int bi, int k0){
    gload16(Ap + k0,           &Asm[bi][t*8]);
    gload16(Ap + 64*K + k0,    &Asm[bi][2048 + t*8]);
    gload16(Bp + k0,           &Bsm[bi][t*8]);
    gload16(Bp + 64*K + k0,    &Bsm[bi][2048 + t*8]);
  };

  float4v acc[4][4];
  #pragma unroll
  for (int i = 0; i < 4; i++)
    #pragma unroll
    for (int j = 0; j < 4; j++) acc[i][j] = (float4v){0.f,0.f,0.f,0.f};

  const int nit = K >> 5;
  stage(0, 0);
  stage(1, 32);

  const int qsw = ((q ^ ((r16 >> 1) & 3)) << 3);  // swizzled k-chunk for ds_read

  for (int it = 0; it < nit; ++it){
    if (it + 2 < nit){
      stage((it + 2) % 3, (it + 2) << 5);
      asm volatile("" ::: "memory");
      asm volatile("s_waitcnt vmcnt(8)" ::: "memory");
    } else if (it + 1 < nit){
      asm volatile("s_waitcnt vmcnt(4)" ::: "memory");
    } else {
      asm volatile("s_waitcnt vmcnt(0)" ::: "memory");
    }
    __builtin_amdgcn_s_barrier();
    asm volatile("" ::: "memory");

    const unsigned short* As = Asm[it % 3];
    const unsigned short* Bs = Bsm[it % 3];
    short8 afr[4], bfr[4];
    #pragma unroll
    for (int i = 0; i < 4; i++) afr[i] = *(const short8*)&As[(wc*64 + i*16 + r16)*32 + qsw];
    #pragma unroll
    for (int j = 0; j < 4; j++) bfr[j] = *(const short8*)&Bs[(wsd*64 + j*16 + r16)*32 + qsw];
    #pragma unroll
    for (int i = 0; i < 4; i++)
      #pragma unroll
      for (int j = 0; j < 4; j++)
        acc[i][j] = __builtin_amdgcn_mfma_f32_16x16x32_bf16(afr[i], bfr[j], acc[i][j], 0, 0, 0);

    asm volatile("" ::: "memory");
    __builtin_amdgcn_s_barrier();
  }

  // ---- LDS-transpose epilogue ----
  if (EMODE == 1 && n0 < 1024){
    // h-half: output HST[b][l][1024] -> per-lane 8-n runs (128B-contiguous per 8 lanes)
    float* Cf = (float*)SMEMraw;    // [128][68]
    #pragma unroll
    for (int h = 0; h < 2; h++){
      __syncthreads();
      if (wc == h){
        #pragma unroll
        for (int j = 0; j < 4; j++){
          int m = wsd*64 + j*16 + r16;
          #pragma unroll
          for (int i = 0; i < 4; i++)
            *(float4v*)&Cf[m*68 + i*16 + q*4] = acc[i][j];
        }
      }
      __syncthreads();
      #pragma unroll
      for (int p = 0; p < 4; p++){
        int m = (t >> 3) + p*32;
        int n8 = (t & 7)*8;
        int gm = m0 + m; int b = gm >> 11, l = gm & 2047;
        float4v v0 = *(const float4v*)&Cf[m*68 + n8];
        float4v v1 = *(const float4v*)&Cf[m*68 + n8 + 4];
        short8 o;
        #pragma unroll
        for (int e = 0; e < 4; e++){ o[e] = f2bf(silu_g(v0[e])); o[e+4] = f2bf(silu_g(v1[e])); }
        *(short8*)&g.O1[((long)(b*2048 + l))*1024 + (n0 + h*64 + n8)] = o;
      }
    }
  } else {
    // [n][l] outputs: per-lane 8-l runs (256B-contiguous per 16 lanes)
    float* Csm = (float*)SMEMraw;   // [32][132]
    #pragma unroll
    for (int qtr = 0; qtr < 4; qtr++){
      __syncthreads();
      if (wc == (qtr >> 1)){
        #pragma unroll
        for (int ii = 0; ii < 2; ii++){
          int i = (qtr & 1)*2 + ii;
          #pragma unroll
          for (int j = 0; j < 4; j++){
            int m = wsd*64 + j*16 + r16;
            #pragma unroll
            for (int rg = 0; rg < 4; rg++)
              Csm[(ii*16 + q*4 + rg)*132 + m] = acc[i][j][rg];
          }
        }
      }
      __syncthreads();
      #pragma unroll
      for (int sp = 0; sp < 2; sp++){
        int nrow = (t >> 4) + sp*16;
        int n = n0 + qtr*32 + nrow;
        int m8 = (t & 15)*8;
        int gm = m0 + m8; int b = gm >> 11, l = gm & 2047;
        float4v v0 = *(const float4v*)&Csm[nrow*132 + m8];
        float4v v1 = *(const float4v*)&Csm[nrow*132 + m8 + 4];
        short8 o;
        #pragma unroll
        for (int e = 0; e < 4; e++){ o[e] = f2bf(v0[e]); o[e+4] = f2bf(v1[e]); }
        if (EMODE == 1) *(short8*)&g.O2[((long)(b*1024 + (n - 1024)))*2048 + l] = o;
        else            *(short8*)&g.O1[((long)(b*2048 + n))*2048 + l] = o;
      }
    }
  }
}

// ---------------- bf16 MFMA fused GEMM (128x128 tile, register-prefetched K-loop) ----------------
// BMODE: 0 = bf16 copy (windowed/zero-padded), 2 = audio closed-form (b0 conv1)
// EMODE: 1 bf16 store, 2 mp_add auxXH(bf16)->bf16, 3 mp_add audio-proj->bf16
struct GemmArgs {
  const unsigned short* A;       // pre-normalized bf16 weights, row-major K
  const unsigned short* Bh;      // bf16 B source
  const float* invn; const float* audio;
  const float* pw; const float* pb;
  const unsigned short* auxXH;
  unsigned short* CoutH; unsigned short* Cout2H;
  int N, K, Fdim, Lw, lq0, BLw, Bl0, CLw, Cl0, Nsto, Fsrc;
};

template<int BMODE, int EMODE>
__global__ __launch_bounds__(256,2) void mgemm_kernel(GemmArgs g){
  __shared__ __align__(16) char SMEMraw[20480];
  unsigned short* Asm = (unsigned short*)SMEMraw;       // [128*40]
  unsigned short* Bsm = Asm + 128*40;                   // [128*40]
  const int t = threadIdx.x;
  const int lane = t & 63;
  const int wave = t >> 6;
  const int wc = wave >> 1, wsd = wave & 1;
  const int q = lane >> 4, r16 = lane & 15;
  const int s0 = blockIdx.x * 128;
  const int n0 = blockIdx.y * 128;
  const int FL = g.Fdim * g.Lw;

  // A staging mapping
  const int ar = t >> 1, ah = t & 1;
  const int an = n0 + ar;
  const bool aval = an < g.N;
  const unsigned short* Aptr = g.A + (long)an*g.K + ah*16;

  // B staging mapping: (k-group kg 0..7 of 4k, m-group mg 0..31 of 4m)
  const int kg = t & 7, mg = t >> 3;
  const int mb = s0 + mg*4;
  int bcol = mb / FL; int rr = mb - bcol*FL;
  int fcol = (g.Fdim > 1) ? (rr / g.Lw) : 0;
  int labs = g.lq0 + (rr - fcol*g.Lw);
  const bool cv = (bcol < 2);
  bool lv[4];
  #pragma unroll
  for (int j = 0; j < 4; j++) lv[j] = cv && (labs + j >= 0) && (labs + j < 2048);
  const bool vec4 = cv && (labs >= 0) && (labs + 3 < 2048);
  const unsigned short* bbase = g.Bh;
  if (cv) bbase = g.Bh + ((long)(bcol*g.K)*g.Fsrc + fcol)*g.BLw + (labs - g.Bl0);
  const long kstep = (long)g.Fsrc * g.BLw;

  float invn4[4] = {0,0,0,0}, aud4[4] = {0,0,0,0};
  if (BMODE == 2){
    #pragma unroll
    for (int j = 0; j < 4; j++) if (lv[j]){
      invn4[j] = g.invn[(bcol*g.Fdim + fcol)*2048 + labs + j];
      aud4[j]  = g.audio[(bcol*128 + fcol)*2048 + labs + j];
    }
  }

  float4v acc[4][4];
  #pragma unroll
  for (int i = 0; i < 4; i++)
    #pragma unroll
    for (int j = 0; j < 4; j++) acc[i][j] = (float4v){0.f,0.f,0.f,0.f};

  // prefetch registers
  short8 pa0 = {0,0,0,0,0,0,0,0}, pa1 = {0,0,0,0,0,0,0,0};
  short4v praw[4];
  #pragma unroll
  for (int i = 0; i < 4; i++) praw[i] = (short4v){0,0,0,0};

  auto ldA = [&](int kb){
    if (aval){
      pa0 = *(const short8*)(Aptr + kb);
      pa1 = *(const short8*)(Aptr + kb + 8);
    }
  };
  auto ldB = [&](int kb){
    #pragma unroll
    for (int i = 0; i < 4; i++){
      const int k = kb + kg*4 + i;
      const unsigned short* bp = bbase + (long)k*kstep;
      if (vec4) praw[i] = *(const short4v*)bp;
      else {
        short4v u = {0,0,0,0};
        #pragma unroll
        for (int j = 0; j < 4; j++) if (lv[j]) u[j] = (short)bp[j];
        praw[i] = u;
      }
    }
  };

  ldA(0);
  if (BMODE == 0) ldB(0);

  for (int k0 = 0; k0 < g.K; k0 += 32){
    short8 sa0 = pa0, sa1 = pa1;
    short4v bpk[4];
    if (BMODE == 0){
      #pragma unroll
      for (int j = 0; j < 4; j++){
        short4v p;
        #pragma unroll
        for (int i = 0; i < 4; i++) p[i] = praw[i][j];
        bpk[j] = p;
      }
    } else { // BMODE == 2
      float tv[4][4];
      #pragma unroll
      for (int i = 0; i < 4; i++){
        const int k = k0 + kg*4 + i;
        const float pwk = g.pw[k], pbk = g.pb[k];
        #pragma unroll
        for (int j = 0; j < 4; j++) tv[i][j] = lv[j] ? silu_g((aud4[j]*pwk + pbk)*invn4[j]) : 0.f;
      }
      #pragma unroll
      for (int j = 0; j < 4; j++){
        short4v p;
        #pragma unroll
        for (int i = 0; i < 4; i++) p[i] = f2bf(tv[i][j]);
        bpk[j] = p;
      }
    }
    if (k0 + 32 < g.K){
      ldA(k0 + 32);
      if (BMODE == 0) ldB(k0 + 32);
    }

    __syncthreads();
    *(short8*)&Asm[ar*40 + ah*16]     = sa0;
    *(short8*)&Asm[ar*40 + ah*16 + 8] = sa1;
    #pragma unroll
    for (int j = 0; j < 4; j++)
      *(short4v*)&Bsm[(mg*4 + j)*40 + kg*4] = bpk[j];
    __syncthreads();

    short8 afr[4], bfr[4];
    #pragma unroll
    for (int i = 0; i < 4; i++) afr[i] = *(const short8*)&Asm[(wc*64 + i*16 + r16)*40 + q*8];
    #pragma unroll
    for (int j = 0; j < 4; j++) bfr[j] = *(const short8*)&Bsm[(wsd*64 + j*16 + r16)*40 + q*8];
    #pragma unroll
    for (int i = 0; i < 4; i++)
      #pragma unroll
      for (int j = 0; j < 4; j++)
        acc[i][j] = __builtin_amdgcn_mfma_f32_16x16x32_bf16(afr[i], bfr[j], acc[i][j], 0, 0, 0);
  }

  // ---- LDS-transpose epilogue: quarters of 32 n-rows, coalesced short8 stores ----
  {
    float* Csm = (float*)SMEMraw;   // [32][132]
    #pragma unroll
    for (int qtr = 0; qtr < 4; qtr++){
      __syncthreads();
      if (wc == (qtr >> 1)){
        #pragma unroll
        for (int ii = 0; ii < 2; ii++){
          int i = (qtr & 1)*2 + ii;
          #pragma unroll
          for (int j = 0; j < 4; j++){
            int m = wsd*64 + j*16 + r16;
            #pragma unroll
            for (int rg = 0; rg < 4; rg++)
              Csm[(ii*16 + q*4 + rg)*132 + m] = acc[i][j][rg];
          }
        }
      }
      __syncthreads();
      #pragma unroll
      for (int sp = 0; sp < 2; sp++){
        int nrow = (t >> 4) + sp*16;
        int n = n0 + qtr*32 + nrow;
        int m8 = (t & 15)*8;
        if (n >= g.N) continue;
        int sg = s0 + m8;
        int b2 = sg / FL; int r2 = sg - b2*FL;
        if (b2 >= 2) continue;
        int f2 = (g.Fdim > 1) ? (r2 / g.Lw) : 0;
        int l2 = g.lq0 + (r2 - f2*g.Lw);
        float4v v0 = *(const float4v*)&Csm[nrow*132 + m8];
        float4v v1 = *(const float4v*)&Csm[nrow*132 + m8 + 4];
        long obase = ((long)(b2*g.Nsto + n)*g.Fdim + f2)*g.CLw + (l2 - g.Cl0);
        short8 o;
        if (EMODE == 1){
          #pragma unroll
          for (int e = 0; e < 4; e++){ o[e] = f2bf(v0[e]); o[e+4] = f2bf(v1[e]); }
        } else if (EMODE == 2){
          short8 axv = *(const short8*)&g.auxXH[((long)(b2*g.N + n)*g.Fdim + f2)*2048 + l2];
          const float* ivp = &g.invn[(b2*g.Fdim + f2)*2048 + l2];
          float4v iv0 = *(const float4v*)ivp;
          float4v iv1 = *(const float4v*)(ivp + 4);
          #pragma unroll
          for (int e = 0; e < 4; e++){
            float xn0 = bf2f((unsigned short)axv[e]) * iv0[e];
            float xn1 = bf2f((unsigned short)axv[e+4]) * iv1[e];
            o[e]   = f2bf((xn0*0.7f + v0[e]*0.3f)*MPS);
            o[e+4] = f2bf((xn1*0.7f + v1[e]*0.3f)*MPS);
          }
        } else { // EMODE == 3
          float pwn = g.pw[n], pbn = g.pb[n];
          const float* ap  = &g.audio[(b2*128 + f2)*2048 + l2];
          const float* ivp = &g.invn[(b2*g.Fdim + f2)*2048 + l2];
          float4v a0 = *(const float4v*)ap,  a1 = *(const float4v*)(ap + 4);
          float4v iv0 = *(const float4v*)ivp, iv1 = *(const float4v*)(ivp + 4);
          #pragma unroll
          for (int e = 0; e < 4; e++){
            float xn0 = (a0[e]*pwn + pbn)*iv0[e];
            float xn1 = (a1[e]*pwn + pbn)*iv1[e];
            o[e]   = f2bf((xn0*0.7f + v0[e]*0.3f)*MPS);
            o[e+4] = f2bf((xn1*0.7f + v1[e]*0.3f)*MPS);
          }
        }
        *(short8*)&g.CoutH[obase] = o;
      }
    }
  }
}

// ---------------- downsample conv GEMM: 64x64 tile on pooled P, prefetched ----------------
// EMODE 0: f32 store full-L ; EMODE 1: bf16 store full-L
// LDS-transpose epilogue for coalesced stores.
struct DnArgs {
  const unsigned short* A; const unsigned short* P;
  float* Cout; unsigned short* CoutH;
  int N, K, F2, Lc, l0;
};

template<int EMODE>
__global__ __launch_bounds__(256,4) void mgemm64_kernel(DnArgs g){
  __shared__ __align__(16) char SMEM[10240];
  unsigned short* Asm = (unsigned short*)SMEM;       // [64*40]
  unsigned short* Bsm = Asm + 64*40;
  const int t = threadIdx.x;
  const int lane = t & 63;
  const int wave = t >> 6;
  const int wc = wave >> 1, wsd = wave & 1;
  const int q = lane >> 4, r16 = lane & 15;
  const int s0 = blockIdx.x * 64;
  const int n0 = blockIdx.y * 64;
  const int FL = g.F2 * g.Lc;

  const int ar = t >> 2, ah = t & 3;
  const unsigned short* Aptr = g.A + (long)(n0 + ar)*g.K + ah*8;
  const int kg = t & 7, mg = t >> 3;
  const bool bstage = (mg < 16);
  const int mb = s0 + (mg & 15)*4;
  const int bcol = mb / FL; const int rr = mb - bcol*FL;
  const int fcol = rr / g.Lc; const int li = rr - fcol*g.Lc;
  const unsigned short* bbase = g.P + ((long)(bcol*g.K)*g.F2 + fcol)*g.Lc + li;
  const long kstep = (long)g.F2 * g.Lc;

  float4v acc[2][2];
  #pragma unroll
  for (int i = 0; i < 2; i++)
    #pragma unroll
    for (int j = 0; j < 2; j++) acc[i][j] = (float4v){0.f,0.f,0.f,0.f};

  short8 pa = {0,0,0,0,0,0,0,0};
  short4v praw[4];
  #pragma unroll
  for (int i = 0; i < 4; i++) praw[i] = (short4v){0,0,0,0};

  auto ldA = [&](int kb){ pa = *(const short8*)(Aptr + kb); };
  auto ldB = [&](int kb){
    if (bstage){
      #pragma unroll
      for (int i = 0; i < 4; i++)
        praw[i] = *(const short4v*)(bbase + (long)(kb + kg*4 + i)*kstep);
    }
  };
  ldA(0); ldB(0);

  for (int k0 = 0; k0 < g.K; k0 += 32){
    short8 sa = pa;
    short4v bpk[4];
    #pragma unroll
    for (int j = 0; j < 4; j++){
      short4v p;
      #pragma unroll
      for (int i = 0; i < 4; i++) p[i] = praw[i][j];
      bpk[j] = p;
    }
    if (k0 + 32 < g.K){ ldA(k0 + 32); ldB(k0 + 32); }

    __syncthreads();
    *(short8*)&Asm[ar*40 + ah*8] = sa;
    if (bstage){
      #pragma unroll
      for (int j = 0; j < 4; j++)
        *(short4v*)&Bsm[((mg & 15)*4 + j)*40 + kg*4] = bpk[j];
    }
    __syncthreads();

    short8 afr[2], bfr[2];
    #pragma unroll
    for (int i = 0; i < 2; i++) afr[i] = *(const short8*)&Asm[(wc*32 + i*16 + r16)*40 + q*8];
    #pragma unroll
    for (int j = 0; j < 2; j++) bfr[j] = *(const short8*)&Bsm[(wsd*32 + j*16 + r16)*40 + q*8];
    #pragma unroll
    for (int i = 0; i < 2; i++)
      #pragma unroll
      for (int j = 0; j < 2; j++)
        acc[i][j] = __builtin_amdgcn_mfma_f32_16x16x32_bf16(afr[i], bfr[j], acc[i][j], 0, 0, 0);
  }

  // ---- LDS-transpose epilogue: quarters of 16 n-rows ----
  {
    float* Csm = (float*)SMEM;   // [16][68]
    const int b2 = s0 / FL; const int r20 = s0 - b2*FL;
    const int f2c = r20 / g.Lc; const int l2c = g.l0 + (r20 - f2c*g.Lc);
    #pragma unroll
    for (int nq = 0; nq < 4; nq++){
      __syncthreads();
      if (wc == (nq >> 1)){
        const int i = nq & 1;
        #pragma unroll
        for (int j = 0; j < 2; j++)
          #pragma unroll
          for (int rg = 0; rg < 4; rg++)
            Csm[(q*4 + rg)*68 + wsd*32 + j*16 + r16] = acc[i][j][rg];
      }
      __syncthreads();
      int nrow = t >> 4;
      int mq = (t & 15)*4;
      int n = n0 + nq*16 + nrow;
      float4v v = *(const float4v*)&Csm[nrow*68 + mq];
      long oidx = ((long)(b2*g.N + n)*g.F2 + f2c)*2048 + l2c + mq;
      if (EMODE == 0){
        *(float4v*)&g.Cout[oidx] = v;
      } else {
        short4v o = { f2bf(v[0]), f2bf(v[1]), f2bf(v[2]), f2bf(v[3]) };
        *(short4v*)&g.CoutH[oidx] = o;
      }
    }
  }
}

// ---------------- seq out GEMM: 64x64 tile, Fdim=1, prefetched ----------------
// EMODE 5: mp_add -> f32 Cout ; EMODE 6: mp_add + silu -> f32 Cout
// LDS-transpose epilogue for coalesced f32x4 stores + vector aux/invn reads.
template<int EMODE>
__global__ __launch_bounds__(256,4) void seqout_kernel(const unsigned short* __restrict__ A,
                                                       const unsigned short* __restrict__ Bh,
                                                       const float* __restrict__ invn,
                                                       const float* __restrict__ auxX,
                                                       float* __restrict__ Cout, int K){
  __shared__ __align__(16) char SMEM[10240];
  unsigned short* Asm = (unsigned short*)SMEM;       // [64*40]
  unsigned short* Bsm = Asm + 64*40;
  const int t = threadIdx.x;
  const int lane = t & 63;
  const int wave = t >> 6;
  const int wc = wave >> 1, wsd = wave & 1;
  const int q = lane >> 4, r16 = lane & 15;
  const int s0 = blockIdx.x * 64;
  const int n0 = blockIdx.y * 64;

  const int ar = t >> 2, ah = t & 3;
  const unsigned short* Aptr = A + (long)(n0 + ar)*K + ah*8;
  const int kg = t & 7, mg = t >> 3;
  const bool bstage = (mg < 16);
  const int mb = s0 + (mg & 15)*4;
  const int bcol = mb >> 11, lb = mb & 2047;
  const unsigned short* bbase = Bh + ((long)bcol*K)*2048 + lb;

  float4v acc[2][2];
  #pragma unroll
  for (int i = 0; i < 2; i++)
    #pragma unroll
    for (int j = 0; j < 2; j++) acc[i][j] = (float4v){0.f,0.f,0.f,0.f};

  short8 pa = {0,0,0,0,0,0,0,0};
  short4v praw[4];
  #pragma unroll
  for (int i = 0; i < 4; i++) praw[i] = (short4v){0,0,0,0};

  auto ldA = [&](int kb){ pa = *(const short8*)(Aptr + kb); };
  auto ldB = [&](int kb){
    if (bstage){
      #pragma unroll
      for (int i = 0; i < 4; i++)
        praw[i] = *(const short4v*)(bbase + (long)(kb + kg*4 + i)*2048);
    }
  };
  ldA(0); ldB(0);

  for (int k0 = 0; k0 < K; k0 += 32){
    short8 sa = pa;
    short4v bpk[4];
    #pragma unroll
    for (int j = 0; j < 4; j++){
      short4v p;
      #pragma unroll
      for (int i = 0; i < 4; i++) p[i] = praw[i][j];
      bpk[j] = p;
    }
    if (k0 + 32 < K){ ldA(k0 + 32); ldB(k0 + 32); }

    __syncthreads();
    *(short8*)&Asm[ar*40 + ah*8] = sa;
    if (bstage){
      #pragma unroll
      for (int j = 0; j < 4; j++)
        *(short4v*)&Bsm[((mg & 15)*4 + j)*40 + kg*4] = bpk[j];
    }
    __syncthreads();

    short8 afr[2], bfr[2];
    #pragma unroll
    for (int i = 0; i < 2; i++) afr[i] = *(const short8*)&Asm[(wc*32 + i*16 + r16)*40 + q*8];
    #pragma unroll
    for (int j = 0; j < 2; j++) bfr[j] = *(const short8*)&Bsm[(wsd*32 + j*16 + r16)*40 + q*8];
    #pragma unroll
    for (int i = 0; i < 2; i++)
      #pragma unroll
      for (int j = 0; j < 2; j++)
        acc[i][j] = __builtin_amdgcn_mfma_f32_16x16x32_bf16(afr[i], bfr[j], acc[i][j], 0, 0, 0);
  }

  // ---- LDS-transpose epilogue ----
  {
    float* Csm = (float*)SMEM;   // [16][68]
    const int b2 = s0 >> 11; const int l0b = s0 & 2047;
    #pragma unroll
    for (int nq = 0; nq < 4; nq++){
      __syncthreads();
      if (wc == (nq >> 1)){
        const int i = nq & 1;
        #pragma unroll
        for (int j = 0; j < 2; j++)
          #pragma unroll
          for (int rg = 0; rg < 4; rg++)
            Csm[(q*4 + rg)*68 + wsd*32 + j*16 + r16] = acc[i][j][rg];
      }
      __syncthreads();
      int nrow = t >> 4;
      int mq = (t & 15)*4;
      int n = n0 + nq*16 + nrow;
      int l = l0b + mq;
      float4v v = *(const float4v*)&Csm[nrow*68 + mq];
      float4v ax = *(const float4v*)&auxX[((long)b2*512 + n)*2048 + l];
      float4v iv = *(const float4v*)&invn[b2*2048 + l];
      float4v r;
      #pragma unroll
      for (int e = 0; e < 4; e++){
        float xn = ax[e]*iv[e];
        float rr = (xn*0.7f + v[e]*0.3f)*MPS;
        r[e] = (EMODE == 6) ? silu_g(rr) : rr;
      }
      *(float4v*)&Cout[((long)b2*512 + n)*2048 + l] = r;
    }
  }
}

// ---------------- freq-pool: P[b,k,f2,l] = mean_p Hb[b,k,f2*s+p,l], bf16 ----------------
__global__ __launch_bounds__(256) void poolf_kernel(const unsigned short* __restrict__ Hb,
                                                    unsigned short* __restrict__ P,
                                                    int F2, int s, int Lc, long total4){
  long i = blockIdx.x*256 + threadIdx.x;
  if (i >= total4) return;
  long e = i*4;
  int li = (int)(e % Lc); long r0 = e / Lc;
  int f2 = (int)(r0 % F2); long r = r0 / F2;        // r = b*Kc + k
  const unsigned short* src = Hb + ((long)r*F2*s + (long)f2*s)*Lc + li;
  float a0=0,a1=0,a2=0,a3=0;
  for (int p = 0; p < s; p++){
    short4v u = *(const short4v*)(src + (long)p*Lc);
    a0 += bf2f((unsigned short)u[0]); a1 += bf2f((unsigned short)u[1]);
    a2 += bf2f((unsigned short)u[2]); a3 += bf2f((unsigned short)u[3]);
  }
  float inv = 1.f/(float)s;
  short4v o = { f2bf(a0*inv), f2bf(a1*inv), f2bf(a2*inv), f2bf(a3*inv) };
  *(short4v*)&P[((long)r*F2 + f2)*Lc + li] = o;
}

// ---------------- depthwise 5x3 conv (+ silu), bf16 in/out ----------------
// 4 f-rows x 8 l per thread; each input row loaded once, feeds up to 3 f-accumulators
struct DwArgs { const unsigned short* R1; const unsigned short* wd; unsigned short* R2; int C, F, Lc, l0; };
__global__ __launch_bounds__(256) void dw2d_kernel(DwArgs a){
  int idx = blockIdx.x*256 + threadIdx.x;
  int Lq = a.Lc >> 3;
  int Fq = a.F >> 2;
  int total = 2*a.C*Fq*Lq;
  if (idx >= total) return;
  int lq = idx % Lq; int r = idx / Lq;
  int fq = r % Fq; r /= Fq;
  int c = r % a.C; int b = r / a.C;
  int f0 = fq*4;
  int labs = a.l0 + lq*8;
  int Lw = a.Lc + 8;
  const unsigned short* base = a.R1 + (long)((b*a.C + c)*a.F)*Lw + (labs - (a.l0 - 4));
  const unsigned short* w = a.wd + c*15;
  float W[5][3];
  #pragma unroll
  for (int tp = 0; tp < 5; tp++)
    #pragma unroll
    for (int j = 0; j < 3; j++) W[tp][j] = bf2f(w[tp*3 + j]);

  const bool llo = (labs > 0);
  const bool lhi = (labs + 8 < 2048);
  float acc[4][8];
  #pragma unroll
  for (int t = 0; t < 4; t++)
    #pragma unroll
    for (int j = 0; j < 8; j++) acc[t][j] = 0.f;

  #pragma unroll
  for (int r8 = 0; r8 < 8; r8++){
    int rrow = f0 - 2 + r8;
    if (rrow < 0 || rrow >= a.F) continue;
    const unsigned short* p = base + (long)rrow*Lw;
    short4v u0 = *(const short4v*)p;
    short4v u1 = *(const short4v*)(p + 4);
    float x[10];
    x[0] = llo ? bf2f(p[-1]) : 0.f;
    x[1] = bf2f((unsigned short)u0[0]); x[2] = bf2f((unsigned short)u0[1]);
    x[3] = bf2f((unsigned short)u0[2]); x[4] = bf2f((unsigned short)u0[3]);
    x[5] = bf2f((unsigned short)u1[0]); x[6] = bf2f((unsigned short)u1[1]);
    x[7] = bf2f((unsigned short)u1[2]); x[8] = bf2f((unsigned short)u1[3]);
    x[9] = lhi ? bf2f(p[8]) : 0.f;
    #pragma unroll
    for (int t = 0; t < 4; t++){
      const int df = r8 - 2 - t;          // compile-time per (r8,t)
      if (df < -2 || df > 2) continue;
      float w0 = W[df+2][0], w1 = W[df+2][1], w2 = W[df+2][2];
      #pragma unroll
      for (int j = 0; j < 8; j++)
        acc[t][j] += w0*x[j] + w1*x[j+1] + w2*x[j+2];
    }
  }

  unsigned short* ob = a.R2 + ((long)((b*a.C + c)*a.F + f0))*a.Lc + (labs - a.l0);
  #pragma unroll
  for (int t = 0; t < 4; t++){
    short8 o;
    #pragma unroll
    for (int j = 0; j < 8; j++) o[j] = f2bf(silu_g(acc[t][j]));
    *(short8*)(ob + (long)t*a.Lc) = o;
  }
}

// ---------------- seq depthwise 3-tap (+ silu), transposed layouts ----------------
__global__ __launch_bounds__(256) void dwseqT_kernel(const unsigned short* __restrict__ HST,
                                                     const unsigned short* __restrict__ w,
                                                     unsigned short* __restrict__ H2T){
  int idx = blockIdx.x*256 + threadIdx.x;
  if (idx >= 2*2048*128) return;
  int c0 = (idx & 127) * 8; long bt = idx >> 7;     // bt = b*2048 + t
  int tt = (int)(bt & 2047);
  const unsigned short* base = HST + bt*1024 + c0;
  short8 zz = {0,0,0,0,0,0,0,0};
  short8 x1 = *(const short8*)base;
  short8 x0 = (tt > 0)    ? *(const short8*)(base - 1024) : zz;
  short8 x2 = (tt < 2047) ? *(const short8*)(base + 1024) : zz;
  const unsigned short* wp = w + c0*3;
  short8 o;
  #pragma unroll
  for (int j = 0; j < 8; j++){
    float w0 = bf2f(wp[3*j]), w1 = bf2f(wp[3*j+1]), w2 = bf2f(wp[3*j+2]);
    float v = w0*bf2f((unsigned short)x0[j]) + w1*bf2f((unsigned short)x1[j]) + w2*bf2f((unsigned short)x2[j]);
    o[j] = f2bf(silu_g(v));
  }
  *(short8*)&H2T[bt*1024 + c0] = o;
}

// ---------------- minGRU scan + gate (bf16 z/c), wave-shuffle scan ----------------
__global__ __launch_bounds__(256) void scan_kernel(const unsigned short* __restrict__ ZC, const unsigned short* __restrict__ G,
                                                   unsigned short* __restrict__ SC){
  int bc = blockIdx.x;            // 0..2047 = b*1024+c
  int b = bc >> 10, c = bc & 1023;
  const unsigned short* zrow = ZC + ((long)(b*2048 + c))*2048;
  const unsigned short* crow = ZC + ((long)(b*2048 + 1024 + c))*2048;
  const unsigned short* grow = G + (long)bc*2048;
  unsigned short* orow = SC + (long)bc*2048;
  int tid = threadIdx.x;
  int t0 = tid*8;
  short8 zv = *(const short8*)&zrow[t0];
  short8 cv = *(const short8*)&crow[t0];
  float av[8], bv[8];
  float A = 1.f, Bv = 0.f;
  #pragma unroll
  for (int j = 0; j < 8; j++){
    float z = bf2f((unsigned short)zv[j]); float cval = bf2f((unsigned short)cv[j]);
    float zs = 1.f/(1.f + __expf(-z));
    float a = 1.f - zs; float bb = zs*cval;
    av[j] = a; bv[j] = bb;
    Bv = a*Bv + bb;
    A = a*A;
  }
  // inclusive scan of (A,Bv) within each 64-lane wave via shfl_up
  // compose(first=(pA,pB), then=(iA,iB)) = (pA*iA, iA*pB + iB)
  int lane = tid & 63, wv = tid >> 6;
  float iA = A, iB = Bv;
  #pragma unroll
  for (int off = 1; off < 64; off <<= 1){
    float pA = __shfl_up(iA, off);
    float pB = __shfl_up(iB, off);
    if (lane >= off){ iB = iA*pB + iB; iA = iA*pA; }
  }
  // exclusive within wave
  float exA = __shfl_up(iA, 1);
  float exB = __shfl_up(iB, 1);
  if (lane == 0){ exA = 1.f; exB = 0.f; }
  // wave totals -> LDS, single barrier
  __shared__ float sWA[4], sWB[4];
  if (lane == 63){ sWA[wv] = iA; sWB[wv] = iB; }
  __syncthreads();
  // exclusive wave prefix (<=3 serial composes)
  float wpA = 1.f, wpB = 0.f;
  #pragma unroll
  for (int w = 0; w < 3; w++){
    if (w < wv){ wpB = sWA[w]*wpB + sWB[w]; wpA = wpA*sWA[w]; }
  }
  // full exclusive prefix B = compose(wp first, ex then).B ; h starts at that value
  float h = exA*wpB + exB;
  short8 gv = *(const short8*)&grow[t0];
  short8 ov;
  #pragma unroll
  for (int j = 0; j < 8; j++){
    h = av[j]*h + bv[j];
    ov[j] = f2bf(h * silu_g(bf2f((unsigned short)gv[j])));
  }
  *(short8*)&orow[t0] = ov;
}

extern "C" void kernel_launch(void* const* d_in, const int* in_sizes, int n_in,
                              void* d_out, int out_size, void* d_ws, size_t ws_size,
                              hipStream_t stream) {
  const float* audio = (const float*)d_in[0];
  const float* pw = (const float*)d_in[1];
  const float* pb = (const float*)d_in[2];
  const float* cw1[3] = {(const float*)d_in[3], (const float*)d_in[7], (const float*)d_in[11]};
  const float* cwd[3] = {(const float*)d_in[4], (const float*)d_in[8], (const float*)d_in[12]};
  const float* cw2[3] = {(const float*)d_in[5], (const float*)d_in[9], (const float*)d_in[13]};
  const float* cdn[3] = {(const float*)d_in[6], (const float*)d_in[10], (const float*)d_in[14]};
  const float* hgw  = (const float*)d_in[15];
  const float* dww  = (const float*)d_in[16];
  const float* gruw = (const float*)d_in[17];
  const float* outw = (const float*)d_in[18];
  float* out = (float*)d_out;

  // ---- workspace layout (bytes) ----
  char* P0 = (char*)d_ws;
  float*          INVW = (float*)P0;                    P0 += 131072;     // S at [32000]
  unsigned short* WBF  = (unsigned short*)P0;           P0 += 30443776;   // 15,221,888 bf16
  float*          INVN = (float*)P0;                    P0 += 2097152;
  char*           XBZC = P0;                            P0 += 33554432;   // XB (conv b1/b2) / ZC bf16 (seq)
  unsigned short* IN1h = (unsigned short*)P0;           P0 += 33554432;   // b0 out bf16; seq scratch later
  unsigned short* IN2h = (unsigned short*)P0;           P0 += 16777216;   // b1 out bf16
  float*          SEQ  = (float*)P0;                    P0 += 8388608;    // b2 out fp32
  char*           ARENA = P0;
  long arenaBytes = (long)ws_size - (long)(P0 - (char*)d_ws);
  float* S = INVW + 32000;

  // weight table (order: cw1/cwd/cw2/cdn x3, hg, dww, gru, out)
  const float* wsrc[16] = {cw1[0],cwd[0],cw2[0],cdn[0], cw1[1],cwd[1],cw2[1],cdn[1],
                           cw1[2],cwd[2],cw2[2],cdn[2], hgw, dww, gruw, outw};
  int Os[16] = {128,128,64,128, 256,256,128,256, 512,512,256,512, 8192,4096,8192,2048};
  int Ks[16] = {64,15,128,64, 128,15,256,128, 256,15,512,256, 512,3,1024,1024};
  int wbfOff[16];
  {
    int wo = 0;
    for (int i = 0; i < 16; i++){ wbfOff[i] = wo; wo += Os[i]*Ks[i]; }
  }
  {
    NcArgs na;
    int rows = 0;
    for (int i = 0; i < 16; i++){
      na.e[i].w = wsrc[i]; na.e[i].O = Os[i]; na.e[i].K = Ks[i]; na.e[i].dstOff = wbfOff[i];
      rows += Os[i];
    }
    normcast_kernel<<<rows, 64, 0, stream>>>(na, WBF);
  }
  projstats_kernel<<<1, 64, 0, stream>>>(pw, pb, S);

  // ---- conv blocks ----
  int Cin_[3]  = {64,128,256};
  int Cmid_[3] = {128,256,512};
  int F_[3]    = {128,32,8};
  int s_[3]    = {4,4,8};
  const unsigned short* XinH[3] = {nullptr, IN1h, IN2h};
  unsigned short* XoutH[3] = {IN1h, IN2h, nullptr};
  int iW1[3]={0,4,8}, iWd[3]={1,5,9}, iW2[3]={2,6,10}, iDn[3]={3,7,11};

  for (int b = 0; b < 3; b++){
    int Cin = Cin_[b], Cmid = Cmid_[b], F = F_[b], s = s_[b];
    int F2 = F/s;
    int nc = 16;
    for (int c = 1; c <= 16; c <<= 1){
      long Lc = 2048/c;
      long bytes = 2L*(2L*Cmid*F*(Lc+8) + 2L*Cmid*F*Lc + 2L*Cin*F*Lc + 2L*Cin*F2*Lc);
      if (bytes <= arenaBytes){ nc = c; break; }
    }
    int Lc = 2048/nc;
    unsigned short* R1 = (unsigned short*)ARENA;
    unsigned short* R2 = R1 + 2L*Cmid*F*(Lc+8);
    unsigned short* Hb = R2 + 2L*Cmid*F*Lc;
    unsigned short* Pb = Hb + 2L*Cin*F*Lc;
    unsigned short* XB = (unsigned short*)XBZC;

    if (b == 0){
      invn_audio_kernel<<<(2*128*2048/4+255)/256, 256, 0, stream>>>(audio, S, INVN);
    } else {
      int positions = 2*F*2048;
      invn_reduce_kernel<8,true><<<positions/32, 256, 0, stream>>>(XinH[b], INVN, Cin, F);
      long total4 = (long)2*Cin*F*2048/4;
      applynorm_kernel<true,true><<<(int)((total4+255)/256), 256, 0, stream>>>(XinH[b], INVN, XB, Cin, F, total4);
    }

    for (int ci = 0; ci < nc; ci++){
      int l0 = ci*Lc;
      // conv1: Cin -> Cmid on window [l0-4, l0+Lc+4) -> R1 bf16
      GemmArgs ga{};
      ga.A = WBF + wbfOff[iW1[b]];
      ga.Bh = XB; ga.invn = INVN; ga.audio = audio; ga.pw = pw; ga.pb = pb;
      ga.CoutH = R1; ga.N = Cmid; ga.K = Cin; ga.Fdim = F; ga.Lw = Lc+8; ga.lq0 = l0-4;
      ga.BLw = 2048; ga.Bl0 = 0; ga.CLw = Lc+8; ga.Cl0 = l0-4; ga.Nsto = Cmid; ga.Fsrc = F;
      int M1 = 2*F*(Lc+8);
      dim3 g1((M1+127)/128, (Cmid+127)/128);
      if (b == 0) mgemm_kernel<2,1><<<g1,256,0,stream>>>(ga);
      else        mgemm_kernel<0,1><<<g1,256,0,stream>>>(ga);
      // depthwise 5x3 + silu -> R2 bf16 (4f x 8l per thread)
      DwArgs da{R1, WBF + wbfOff[iWd[b]], R2, Cmid, F, Lc, l0};
      int tdw = 2*Cmid*(F/4)*(Lc/8);
      dw2d_kernel<<<(tdw+255)/256, 256, 0, stream>>>(da);
      // conv2 + mp_add -> Hb bf16
      GemmArgs gb{};
      gb.A = WBF + wbfOff[iW2[b]];
      gb.Bh = R2; gb.invn = INVN; gb.audio = audio; gb.pw = pw; gb.pb = pb; gb.auxXH = XinH[b];
      gb.CoutH = Hb; gb.N = Cin; gb.K = Cmid; gb.Fdim = F; gb.Lw = Lc; gb.lq0 = l0;
      gb.BLw = Lc; gb.Bl0 = l0; gb.CLw = Lc; gb.Cl0 = l0; gb.Nsto = Cin; gb.Fsrc = F;
      int M2 = 2*F*Lc;
      dim3 g2((M2+127)/128, (Cin+127)/128);
      if (b == 0) mgemm_kernel<0,3><<<g2,256,0,stream>>>(gb);
      else        mgemm_kernel<0,2><<<g2,256,0,stream>>>(gb);
      // freq-pool Hb -> Pb (bf16)
      long tp4 = (2L*Cin*F2*Lc)/4;
      poolf_kernel<<<(int)((tp4+255)/256), 256, 0, stream>>>(Hb, Pb, F2, s, Lc, tp4);
      // dn conv on pooled P -> Xout (bf16 full-L for b0/b1; fp32 SEQ for b2)
      DnArgs dn{};
      dn.A = WBF + wbfOff[iDn[b]]; dn.P = Pb;
      dn.Cout = SEQ; dn.CoutH = XoutH[b];
      dn.N = Cmid; dn.K = Cin; dn.F2 = F2; dn.Lc = Lc; dn.l0 = l0;
      dim3 gdn((2*F2*Lc)/64, Cmid/64);
      if (b == 2) mgemm64_kernel<0><<<gdn,256,0,stream>>>(dn);
      else        mgemm64_kernel<1><<<gdn,256,0,stream>>>(dn);
    }
  }

  // ---- seq blocks: K-major transposed activations (XST/HST/H2T), gemmT for hg & gru ----
  unsigned short* XST = IN1h;                 // [b][2048][512]  bf16
  unsigned short* HST = XST + 2097152;        // [b][2048][1024] bf16
  unsigned short* G   = HST + 4194304;        // [b][1024][2048] bf16
  unsigned short* H2T = G  + 4194304;         // [b][2048][1024] bf16
  unsigned short* SC  = H2T + 4194304;        // [b*1024+c][2048] bf16
  unsigned short* ZCh = (unsigned short*)XBZC;

  for (int i = 0; i < 4; i++){
    invn_reduce_kernel<16,false><<<4096/16, 256, 0, stream>>>(SEQ, INVN, 512, 1);
    normT_kernel<<<dim3(32,8,2), 256, 0, stream>>>(SEQ, INVN, XST);
    // hg conv: N=2048, K=512 ; h half -> silu -> HST (transposed), g half -> G
    GTArgs gh{ WBF + wbfOff[12] + (long)i*2048*512, XST, HST, G, 2048, 512 };
    gemmT_kernel<1><<<dim3(32,16), 256, 0, stream>>>(gh);
    // depthwise 3-tap + silu (transposed in/out)
    dwseqT_kernel<<<2048, 256, 0, stream>>>(HST, WBF + wbfOff[13] + i*1024*3, H2T);
    // gru conv 1024 -> 2048 (z|c) -> ZCh bf16 ([b][2048][l] for scan)
    GTArgs gz{ WBF + wbfOff[14] + (long)i*2048*1024, H2T, ZCh, nullptr, 2048, 1024 };
    gemmT_kernel<0><<<dim3(32,16), 256, 0, stream>>>(gz);
    // scan + gate -> SC bf16
    scan_kernel<<<2048,256,0,stream>>>(ZCh, G, SC);
    // out conv + mp_add -> SEQ (i<3) or mp_add+silu -> d_out (i==3)
    const unsigned short* oA = WBF + wbfOff[15] + (long)i*512*1024;
    if (i < 3) seqout_kernel<5><<<dim3(64,8),256,0,stream>>>(oA, SC, INVN, SEQ, SEQ, 1024);
    else       seqout_kernel<6><<<dim3(64,8),256,0,stream>>>(oA, SC, INVN, SEQ, out, 1024);
  }

  (void)in_sizes; (void)n_in; (void)out_size;
}

// Round 8
// 1089.390 us; speedup vs baseline: 1.1161x; 1.0164x over previous
//
#include <hip/hip_runtime.h>
#include <math.h>

#define GAIN 1.6778523489932886f     // 1/0.596
#define MPS  1.3130643285972254f     // 1/sqrt(0.7^2+0.3^2)

typedef __attribute__((ext_vector_type(8))) short short8;
typedef __attribute__((ext_vector_type(4))) short short4v;
typedef __attribute__((ext_vector_type(4))) float float4v;

__device__ __forceinline__ float silu_g(float x){
  float s = 1.0f/(1.0f + __expf(-x));
  return x*s*GAIN;
}
__device__ __forceinline__ short f2bf(float f){
  unsigned u = __builtin_bit_cast(unsigned, f);
  u += 0x7fffu + ((u >> 16) & 1u);
  return (short)(u >> 16);
}
__device__ __forceinline__ float bf2f(unsigned short h){
  return __builtin_bit_cast(float, ((unsigned)h) << 16);
}

// async global->LDS, 16B per lane (dest is wave-uniform base + lane*16)
typedef __attribute__((address_space(3))) unsigned int as3_uint;
typedef const __attribute__((address_space(1))) unsigned int as1_cuint;
__device__ __forceinline__ void gload16(const unsigned short* gsrc, unsigned short* ldst){
  __builtin_amdgcn_global_load_lds((as1_cuint*)gsrc, (as3_uint*)ldst, 16, 0, 0);
}

// ---------------- fused weight row-norm + bf16 cast (one wave per row) ----------------
struct NcEnt { const float* w; int O, K, dstOff; };
struct NcArgs { NcEnt e[16]; };

__global__ __launch_bounds__(64) void normcast_kernel(NcArgs na, unsigned short* __restrict__ wbf){
  int row = blockIdx.x;
  int base = 0; int i;
  for (i = 0; i < 16; i++){
    if (row < base + na.e[i].O) break;
    base += na.e[i].O;
  }
  if (i >= 16) return;
  int r = row - base; int K = na.e[i].K;
  const float* w = na.e[i].w + (long)r*K;
  unsigned short* dst = wbf + na.e[i].dstOff + (long)r*K;
  int tid = threadIdx.x;
  float s = 0.f;
  const bool v4 = ((K & 3) == 0);
  if (v4){
    for (int k = tid*4; k < K; k += 256){
      float4v v = *(const float4v*)&w[k];
      s += v[0]*v[0] + v[1]*v[1] + v[2]*v[2] + v[3]*v[3];
    }
  } else {
    for (int k = tid; k < K; k += 64){ float v = w[k]; s += v*v; }
  }
  for (int off = 32; off; off >>= 1) s += __shfl_down(s, off);
  float inv = rsqrtf(__shfl(s, 0) + 1e-8f);
  if (v4){
    for (int k = tid*4; k < K; k += 256){
      float4v v = *(const float4v*)&w[k];
      short4v o = { f2bf(v[0]*inv), f2bf(v[1]*inv), f2bf(v[2]*inv), f2bf(v[3]*inv) };
      *(short4v*)&dst[k] = o;
    }
  } else {
    for (int k = tid; k < K; k += 64) dst[k] = (unsigned short)f2bf(w[k]*inv);
  }
}

// ---------------- audio projection stats (one wave) ----------------
__global__ __launch_bounds__(64) void projstats_kernel(const float* __restrict__ pw, const float* __restrict__ pb,
                                                       float* __restrict__ S){
  int t = threadIdx.x;
  float p = pw[t], q = pb[t];
  float s1 = p*p, s2 = p*q, s3 = q*q;
  for (int off = 32; off; off >>= 1){
    s1 += __shfl_down(s1, off); s2 += __shfl_down(s2, off); s3 += __shfl_down(s3, off);
  }
  if (t == 0){ S[0] = s1; S[1] = s2; S[2] = s3; }
}

// ---------------- b0 inverse pixel-norm (closed form, element-wise 4-wide) ----------------
__global__ __launch_bounds__(256) void invn_audio_kernel(const float* __restrict__ audio, const float* __restrict__ S,
                                                         float* __restrict__ invn){
  long i = blockIdx.x*256 + threadIdx.x;
  if (i >= (2L*128*2048)/4) return;
  long e = i*4;
  float S1 = S[0], S2 = S[1], S3 = S[2];
  float4v a = *(const float4v*)&audio[e];
  float4v o;
  #pragma unroll
  for (int j = 0; j < 4; j++) o[j] = rsqrtf((a[j]*a[j]*S1 + 2.f*a[j]*S2 + S3)/64.f + 1e-4f);
  *(float4v*)&invn[e] = o;
}

// ---------------- pixel-norm reduce (fp32 or bf16 source) ----------------
template<int G, bool BF>
__global__ __launch_bounds__(256) void invn_reduce_kernel(const void* __restrict__ Xv, float* __restrict__ invn,
                                                          int C, int F){
  constexpr int L = 256/G;
  int t = threadIdx.x; int cs = t / L; int li = t % L;
  long pos = (long)blockIdx.x*L + li;
  int bf = (int)(pos >> 11); int l = (int)(pos & 2047);
  int b = bf / F; int f = bf - b*F;
  long base = ((long)b*C*F + f)*2048 + l;
  long stride = (long)F*2048;
  float s = 0.f;
  if (BF){
    const unsigned short* X = (const unsigned short*)Xv;
    for (int c = cs; c < C; c += G){ float v = bf2f(X[base + (long)c*stride]); s += v*v; }
  } else {
    const float* X = (const float*)Xv;
    for (int c = cs; c < C; c += G){ float v = X[base + (long)c*stride]; s += v*v; }
  }
  __shared__ float red[256];
  red[t] = s; __syncthreads();
  #pragma unroll
  for (int off = G/2; off > 0; off >>= 1){
    if (cs < off) red[t] += red[t + off*L];
    __syncthreads();
  }
  if (cs == 0) invn[pos] = rsqrtf(red[li]/(float)C + 1e-4f);
}

// ---------------- pixel-norm apply (fallback path; fp32 or bf16 source) ----------------
template<bool SILU, bool BF>
__global__ __launch_bounds__(256) void applynorm_kernel(const void* __restrict__ Xv, const float* __restrict__ invn,
                                                        unsigned short* __restrict__ XB, int C, int F, long total4){
  long i = blockIdx.x*256 + threadIdx.x;
  if (i >= total4) return;
  long e = i*4;
  int l = (int)(e & 2047); long r = e >> 11;      // r = (b*C + c)*F + f
  int f = (int)(r % F); long bc = r / F; int b = (int)(bc / C);
  float4v x;
  if (BF){
    short4v u = *(const short4v*)((const unsigned short*)Xv + e);
    x = (float4v){ bf2f((unsigned short)u[0]), bf2f((unsigned short)u[1]),
                   bf2f((unsigned short)u[2]), bf2f((unsigned short)u[3]) };
  } else {
    x = *(const float4v*)((const float*)Xv + e);
  }
  float4v iv = *(const float4v*)&invn[((long)b*F + f)*2048 + l];
  short4v o;
  #pragma unroll
  for (int j = 0; j < 4; j++){
    float v = x[j]*iv[j];
    o[j] = f2bf(SILU ? silu_g(v) : v);
  }
  *(short4v*)&XB[e] = o;
}

// ---------------- seq pixel-norm + transpose: SEQ f32 [b][512][l] -> XST bf16 [b][l][512] ----------------
__global__ __launch_bounds__(256) void normT_kernel(const float* __restrict__ SEQ,
                                                    const float* __restrict__ invn,
                                                    unsigned short* __restrict__ XST){
  __shared__ float tile[64][65];
  const int l0 = blockIdx.x*64, c0 = blockIdx.y*64, b = blockIdx.z;
  const int t = threadIdx.x;
  const int lr = (t & 15)*4;   // l offset within tile (float4)
  const int cr = t >> 4;       // c row, 16 per pass
  #pragma unroll
  for (int p = 0; p < 4; p++){
    int c = cr + p*16;
    float4v v = *(const float4v*)&SEQ[((long)(b*512 + c0 + c))*2048 + l0 + lr];
    tile[c][lr+0] = v[0]; tile[c][lr+1] = v[1]; tile[c][lr+2] = v[2]; tile[c][lr+3] = v[3];
  }
  __syncthreads();
  const int cc = (t & 7)*8;    // c offset within tile (8 wide)
  const int lw = t >> 3;       // l row, 32 per pass
  #pragma unroll
  for (int p = 0; p < 2; p++){
    int l = lw + p*32;
    float iv = invn[b*2048 + l0 + l];
    short8 o;
    #pragma unroll
    for (int j = 0; j < 8; j++) o[j] = f2bf(tile[cc+j][l] * iv);
    *(short8*)&XST[((long)(b*2048 + l0 + l))*512 + c0 + cc] = o;
  }
}

// ---------------- conv pixel-norm + silu + K-major transpose ----------------
// X [2][C][F][2048] bf16 -> XBT [2][F][2056][C] bf16 (l-slot = labs + 4; OOB labs -> 0)
__global__ __launch_bounds__(256) void normxT_kernel(const unsigned short* __restrict__ X,
                                                     const float* __restrict__ invn,
                                                     unsigned short* __restrict__ XBT,
                                                     int C, int F){
  __shared__ unsigned short tile[64][72];
  const int bf = blockIdx.z;
  const int b = bf / F, f = bf - b*F;
  const int c0 = blockIdx.y * 64;
  const int lA = blockIdx.x * 64 - 64;    // labs tile start in [-64, 2048]
  const int t = threadIdx.x;
  const int lr8 = (t & 7)*8, cr = t >> 3;
  #pragma unroll
  for (int p = 0; p < 2; p++){
    int c = c0 + cr + p*32;
    int labs = lA + lr8;
    short8 v = {0,0,0,0,0,0,0,0};
    if (labs >= 0 && labs < 2048){
      short8 u = *(const short8*)&X[((long)(b*C + c)*F + f)*2048 + labs];
      const float* ivp = &invn[((long)b*F + f)*2048 + labs];
      float4v iv0 = *(const float4v*)ivp;
      float4v iv1 = *(const float4v*)(ivp + 4);
      #pragma unroll
      for (int j = 0; j < 4; j++){
        v[j]   = f2bf(silu_g(bf2f((unsigned short)u[j])   * iv0[j]));
        v[j+4] = f2bf(silu_g(bf2f((unsigned short)u[j+4]) * iv1[j]));
      }
    }
    *(short8*)&tile[cr + p*32][lr8] = v;
  }
  __syncthreads();
  const int cc = (t & 7)*8, sw = t >> 3;
  #pragma unroll
  for (int p = 0; p < 2; p++){
    int sl = sw + p*32;
    int s = lA + sl + 4;                  // slot index
    if (s < 0 || s >= 2056) continue;
    short8 o;
    #pragma unroll
    for (int j = 0; j < 8; j++) o[j] = (short)tile[cc + j][sl];
    *(short8*)&XBT[(((long)bf)*2056 + s)*C + c0 + cc] = o;
  }
}

// ---------------- K-major fused GEMM for seq blocks ----------------
// A: [N][K] bf16 (normalized weights), B: [M][K] bf16 (M = b*2048 + l)
// EMODE 0 (gz): O1 = ZCh [b][2048][l]
// EMODE 1 (gh): n<1024 -> silu -> O1 = HST [b][l][1024] (packed), else raw -> O2 = G [b][1024][l]
struct GTArgs {
  const unsigned short* A;
  const unsigned short* B;
  unsigned short* O1;
  unsigned short* O2;
  int N, K;
};

template<int EMODE>
__global__ __launch_bounds__(256,2) void gemmT_kernel(GTArgs g){
  __shared__ __align__(16) char SMEMraw[49152];
  unsigned short (*Asm)[4096] = (unsigned short (*)[4096])SMEMraw;            // [3][128*32]
  unsigned short (*Bsm)[4096] = (unsigned short (*)[4096])(SMEMraw + 24576);
  const int t = threadIdx.x;
  const int lane = t & 63;
  const int wc = (t >> 7) & 1;        // N-half
  const int wsd = (t >> 6) & 1;       // M-half
  const int q = lane >> 4, r16 = lane & 15;
  const int m0 = blockIdx.x * 128;
  const int n0 = blockIdx.y * 128;
  const int K = g.K;

  const int r0 = t >> 2;
  const int c8 = (((t & 3) ^ ((r0 >> 1) & 3)) << 3);
  const unsigned short* Ap = g.A + (long)(n0 + r0)*K + c8;
  const unsigned short* Bp = g.B + (long)(m0 + r0)*K + c8;

  auto stage = [&](int bi, int k0){
    gload16(Ap + k0,           &Asm[bi][t*8]);
    gload16(Ap + 64*K + k0,    &Asm[bi][2048 + t*8]);
    gload16(Bp + k0,           &Bsm[bi][t*8]);
    gload16(Bp + 64*K + k0,    &Bsm[bi][2048 + t*8]);
  };

  float4v acc[4][4];
  #pragma unroll
  for (int i = 0; i < 4; i++)
    #pragma unroll
    for (int j = 0; j < 4; j++) acc[i][j] = (float4v){0.f,0.f,0.f,0.f};

  const int nit = K >> 5;
  stage(0, 0);
  stage(1, 32);

  const int qsw = ((q ^ ((r16 >> 1) & 3)) << 3);  // swizzled k-chunk for ds_read

  for (int it = 0; it < nit; ++it){
    if (it + 2 < nit){
      stage((it + 2) % 3, (it + 2) << 5);
      asm volatile("" ::: "memory");
      asm volatile("s_waitcnt vmcnt(8)" ::: "memory");
    } else if (it + 1 < nit){
      asm volatile("s_waitcnt vmcnt(4)" ::: "memory");
    } else {
      asm volatile("s_waitcnt vmcnt(0)" ::: "memory");
    }
    __builtin_amdgcn_s_barrier();
    asm volatile("" ::: "memory");

    const unsigned short* As = Asm[it % 3];
    const unsigned short* Bs = Bsm[it % 3];
    short8 afr[4], bfr[4];
    #pragma unroll
    for (int i = 0; i < 4; i++) afr[i] = *(const short8*)&As[(wc*64 + i*16 + r16)*32 + qsw];
    #pragma unroll
    for (int j = 0; j < 4; j++) bfr[j] = *(const short8*)&Bs[(wsd*64 + j*16 + r16)*32 + qsw];
    #pragma unroll
    for (int i = 0; i < 4; i++)
      #pragma unroll
      for (int j = 0; j < 4; j++)
        acc[i][j] = __builtin_amdgcn_mfma_f32_16x16x32_bf16(afr[i], bfr[j], acc[i][j], 0, 0, 0);

    asm volatile("" ::: "memory");
    __builtin_amdgcn_s_barrier();
  }

  // ---- LDS-transpose epilogue ----
  if (EMODE == 1 && n0 < 1024){
    float* Cf = (float*)SMEMraw;    // [128][68]
    #pragma unroll
    for (int h = 0; h < 2; h++){
      __syncthreads();
      if (wc == h){
        #pragma unroll
        for (int j = 0; j < 4; j++){
          int m = wsd*64 + j*16 + r16;
          #pragma unroll
          for (int i = 0; i < 4; i++)
            *(float4v*)&Cf[m*68 + i*16 + q*4] = acc[i][j];
        }
      }
      __syncthreads();
      #pragma unroll
      for (int p = 0; p < 4; p++){
        int m = (t >> 3) + p*32;
        int n8 = (t & 7)*8;
        int gm = m0 + m; int b = gm >> 11, l = gm & 2047;
        float4v v0 = *(const float4v*)&Cf[m*68 + n8];
        float4v v1 = *(const float4v*)&Cf[m*68 + n8 + 4];
        short8 o;
        #pragma unroll
        for (int e = 0; e < 4; e++){ o[e] = f2bf(silu_g(v0[e])); o[e+4] = f2bf(silu_g(v1[e])); }
        *(short8*)&g.O1[((long)(b*2048 + l))*1024 + (n0 + h*64 + n8)] = o;
      }
    }
  } else {
    float* Csm = (float*)SMEMraw;   // [32][132]
    #pragma unroll
    for (int qtr = 0; qtr < 4; qtr++){
      __syncthreads();
      if (wc == (qtr >> 1)){
        #pragma unroll
        for (int ii = 0; ii < 2; ii++){
          int i = (qtr & 1)*2 + ii;
          #pragma unroll
          for (int j = 0; j < 4; j++){
            int m = wsd*64 + j*16 + r16;
            #pragma unroll
            for (int rg = 0; rg < 4; rg++)
              Csm[(ii*16 + q*4 + rg)*132 + m] = acc[i][j][rg];
          }
        }
      }
      __syncthreads();
      #pragma unroll
      for (int sp = 0; sp < 2; sp++){
        int nrow = (t >> 4) + sp*16;
        int n = n0 + qtr*32 + nrow;
        int m8 = (t & 15)*8;
        int gm = m0 + m8; int b = gm >> 11, l = gm & 2047;
        float4v v0 = *(const float4v*)&Csm[nrow*132 + m8];
        float4v v1 = *(const float4v*)&Csm[nrow*132 + m8 + 4];
        short8 o;
        #pragma unroll
        for (int e = 0; e < 4; e++){ o[e] = f2bf(v0[e]); o[e+4] = f2bf(v1[e]); }
        if (EMODE == 1) *(short8*)&g.O2[((long)(b*1024 + (n - 1024)))*2048 + l] = o;
        else            *(short8*)&g.O1[((long)(b*2048 + n))*2048 + l] = o;
      }
    }
  }
}

// ---------------- K-major conv1 GEMM (b1/b2): gemmT clone with window indexing ----------------
// A: [N][K] weights; B: XBT [2][F][2056][K] (slot = labs+4); chunk rows m = (b,f,lloc), lloc in [0,Lc8)
// Output R1 [2][N][F][Lc8] bf16.
struct GCArgs {
  const unsigned short* A;
  const unsigned short* XBT;
  unsigned short* R1;
  int N, K, F, Lc8, l0;
};

__global__ __launch_bounds__(256,2) void gemmC_kernel(GCArgs g){
  __shared__ __align__(16) char SMEMraw[49152];
  unsigned short (*Asm)[4096] = (unsigned short (*)[4096])SMEMraw;
  unsigned short (*Bsm)[4096] = (unsigned short (*)[4096])(SMEMraw + 24576);
  const int t = threadIdx.x;
  const int lane = t & 63;
  const int wc = (t >> 7) & 1;
  const int wsd = (t >> 6) & 1;
  const int q = lane >> 4, r16 = lane & 15;
  const int m0 = blockIdx.x * 128;
  const int n0 = blockIdx.y * 128;
  const int K = g.K;
  const int Lc8 = g.Lc8;
  const int FLw = g.F * Lc8;

  const int r0 = t >> 2;
  const int c8 = (((t & 3) ^ ((r0 >> 1) & 3)) << 3);
  const unsigned short* Ap = g.A + (long)(n0 + r0)*K + c8;
  // decompose B rows m0+r0 and m0+r0+64 -> XBT addresses (window shift by l0)
  int mA = m0 + r0;
  int bA = mA / FLw; int rA = mA - bA*FLw; int fA = rA / Lc8; int lA = rA - fA*Lc8;
  const unsigned short* Bp0 = g.XBT + (((long)(bA*g.F + fA))*2056 + g.l0 + lA)*K + c8;
  int mB = mA + 64;
  int bB = mB / FLw; int rB = mB - bB*FLw; int fB = rB / Lc8; int lB = rB - fB*Lc8;
  const unsigned short* Bp1 = g.XBT + (((long)(bB*g.F + fB))*2056 + g.l0 + lB)*K + c8;

  auto stage = [&](int bi, int k0){
    gload16(Ap + k0,        &Asm[bi][t*8]);
    gload16(Ap + 64*K + k0, &Asm[bi][2048 + t*8]);
    gload16(Bp0 + k0,       &Bsm[bi][t*8]);
    gload16(Bp1 + k0,       &Bsm[bi][2048 + t*8]);
  };

  float4v acc[4][4];
  #pragma unroll
  for (int i = 0; i < 4; i++)
    #pragma unroll
    for (int j = 0; j < 4; j++) acc[i][j] = (float4v){0.f,0.f,0.f,0.f};

  const int nit = K >> 5;
  stage(0, 0);
  stage(1, 32);

  const int qsw = ((q ^ ((r16 >> 1) & 3)) << 3);

  for (int it = 0; it < nit; ++it){
    if (it + 2 < nit){
      stage((it + 2) % 3, (it + 2) << 5);
      asm volatile("" ::: "memory");
      asm volatile("s_waitcnt vmcnt(8)" ::: "memory");
    } else if (it + 1 < nit){
      asm volatile("s_waitcnt vmcnt(4)" ::: "memory");
    } else {
      asm volatile("s_waitcnt vmcnt(0)" ::: "memory");
    }
    __builtin_amdgcn_s_barrier();
    asm volatile("" ::: "memory");

    const unsigned short* As = Asm[it % 3];
    const unsigned short* Bs = Bsm[it % 3];
    short8 afr[4], bfr[4];
    #pragma unroll
    for (int i = 0; i < 4; i++) afr[i] = *(const short8*)&As[(wc*64 + i*16 + r16)*32 + qsw];
    #pragma unroll
    for (int j = 0; j < 4; j++) bfr[j] = *(const short8*)&Bs[(wsd*64 + j*16 + r16)*32 + qsw];
    #pragma unroll
    for (int i = 0; i < 4; i++)
      #pragma unroll
      for (int j = 0; j < 4; j++)
        acc[i][j] = __builtin_amdgcn_mfma_f32_16x16x32_bf16(afr[i], bfr[j], acc[i][j], 0, 0, 0);

    asm volatile("" ::: "memory");
    __builtin_amdgcn_s_barrier();
  }

  // ---- epilogue: decompose output row once (depends only on t) ----
  {
    int m8 = (t & 15)*8;
    int gm = m0 + m8;
    int bo = gm / FLw; int ro = gm - bo*FLw; int fo = ro / Lc8; int lo = ro - fo*Lc8;
    long obase0 = (((long)(bo*g.N) * g.F + fo))*Lc8 + lo;   // add n*F*Lc8 per n
    float* Csm = (float*)SMEMraw;   // [32][132]
    #pragma unroll
    for (int qtr = 0; qtr < 4; qtr++){
      __syncthreads();
      if (wc == (qtr >> 1)){
        #pragma unroll
        for (int ii = 0; ii < 2; ii++){
          int i = (qtr & 1)*2 + ii;
          #pragma unroll
          for (int j = 0; j < 4; j++){
            int m = wsd*64 + j*16 + r16;
            #pragma unroll
            for (int rg = 0; rg < 4; rg++)
              Csm[(ii*16 + q*4 + rg)*132 + m] = acc[i][j][rg];
          }
        }
      }
      __syncthreads();
      #pragma unroll
      for (int sp = 0; sp < 2; sp++){
        int nrow = (t >> 4) + sp*16;
        int n = n0 + qtr*32 + nrow;
        float4v v0 = *(const float4v*)&Csm[nrow*132 + m8];
        float4v v1 = *(const float4v*)&Csm[nrow*132 + m8 + 4];
        short8 o;
        #pragma unroll
        for (int e = 0; e < 4; e++){ o[e] = f2bf(v0[e]); o[e+4] = f2bf(v1[e]); }
        *(short8*)&g.R1[obase0 + (long)n*g.F*Lc8] = o;
      }
    }
  }
}

// ---------------- bf16 MFMA fused GEMM (128x128 tile, register-prefetched K-loop) ----------------
// BMODE: 0 = bf16 copy (windowed/zero-padded), 2 = audio closed-form (b0 conv1)
// EMODE: 1 bf16 store, 2 mp_add auxXH(bf16)->bf16, 3 mp_add audio-proj->bf16
struct GemmArgs {
  const unsigned short* A;
  const unsigned short* Bh;
  const float* invn; const float* audio;
  const float* pw; const float* pb;
  const unsigned short* auxXH;
  unsigned short* CoutH; unsigned short* Cout2H;
  int N, K, Fdim, Lw, lq0, BLw, Bl0, CLw, Cl0, Nsto, Fsrc;
};

template<int BMODE, int EMODE>
__global__ __launch_bounds__(256,2) void mgemm_kernel(GemmArgs g){
  __shared__ __align__(16) char SMEMraw[20480];
  unsigned short* Asm = (unsigned short*)SMEMraw;
  unsigned short* Bsm = Asm + 128*40;
  const int t = threadIdx.x;
  const int lane = t & 63;
  const int wave = t >> 6;
  const int wc = wave >> 1, wsd = wave & 1;
  const int q = lane >> 4, r16 = lane & 15;
  const int s0 = blockIdx.x * 128;
  const int n0 = blockIdx.y * 128;
  const int FL = g.Fdim * g.Lw;

  const int ar = t >> 1, ah = t & 1;
  const int an = n0 + ar;
  const bool aval = an < g.N;
  const unsigned short* Aptr = g.A + (long)an*g.K + ah*16;

  const int kg = t & 7, mg = t >> 3;
  const int mb = s0 + mg*4;
  int bcol = mb / FL; int rr = mb - bcol*FL;
  int fcol = (g.Fdim > 1) ? (rr / g.Lw) : 0;
  int labs = g.lq0 + (rr - fcol*g.Lw);
  const bool cv = (bcol < 2);
  bool lv[4];
  #pragma unroll
  for (int j = 0; j < 4; j++) lv[j] = cv && (labs + j >= 0) && (labs + j < 2048);
  const bool vec4 = cv && (labs >= 0) && (labs + 3 < 2048);
  const unsigned short* bbase = g.Bh;
  if (cv) bbase = g.Bh + ((long)(bcol*g.K)*g.Fsrc + fcol)*g.BLw + (labs - g.Bl0);
  const long kstep = (long)g.Fsrc * g.BLw;

  float invn4[4] = {0,0,0,0}, aud4[4] = {0,0,0,0};
  if (BMODE == 2){
    #pragma unroll
    for (int j = 0; j < 4; j++) if (lv[j]){
      invn4[j] = g.invn[(bcol*g.Fdim + fcol)*2048 + labs + j];
      aud4[j]  = g.audio[(bcol*128 + fcol)*2048 + labs + j];
    }
  }

  float4v acc[4][4];
  #pragma unroll
  for (int i = 0; i < 4; i++)
    #pragma unroll
    for (int j = 0; j < 4; j++) acc[i][j] = (float4v){0.f,0.f,0.f,0.f};

  short8 pa0 = {0,0,0,0,0,0,0,0}, pa1 = {0,0,0,0,0,0,0,0};
  short4v praw[4];
  #pragma unroll
  for (int i = 0; i < 4; i++) praw[i] = (short4v){0,0,0,0};

  auto ldA = [&](int kb){
    if (aval){
      pa0 = *(const short8*)(Aptr + kb);
      pa1 = *(const short8*)(Aptr + kb + 8);
    }
  };
  auto ldB = [&](int kb){
    #pragma unroll
    for (int i = 0; i < 4; i++){
      const int k = kb + kg*4 + i;
      const unsigned short* bp = bbase + (long)k*kstep;
      if (vec4) praw[i] = *(const short4v*)bp;
      else {
        short4v u = {0,0,0,0};
        #pragma unroll
        for (int j = 0; j < 4; j++) if (lv[j]) u[j] = (short)bp[j];
        praw[i] = u;
      }
    }
  };

  ldA(0);
  if (BMODE == 0) ldB(0);

  for (int k0 = 0; k0 < g.K; k0 += 32){
    short8 sa0 = pa0, sa1 = pa1;
    short4v bpk[4];
    if (BMODE == 0){
      #pragma unroll
      for (int j = 0; j < 4; j++){
        short4v p;
        #pragma unroll
        for (int i = 0; i < 4; i++) p[i] = praw[i][j];
        bpk[j] = p;
      }
    } else { // BMODE == 2
      float tv[4][4];
      #pragma unroll
      for (int i = 0; i < 4; i++){
        const int k = k0 + kg*4 + i;
        const float pwk = g.pw[k], pbk = g.pb[k];
        #pragma unroll
        for (int j = 0; j < 4; j++) tv[i][j] = lv[j] ? silu_g((aud4[j]*pwk + pbk)*invn4[j]) : 0.f;
      }
      #pragma unroll
      for (int j = 0; j < 4; j++){
        short4v p;
        #pragma unroll
        for (int i = 0; i < 4; i++) p[i] = f2bf(tv[i][j]);
        bpk[j] = p;
      }
    }
    if (k0 + 32 < g.K){
      ldA(k0 + 32);
      if (BMODE == 0) ldB(k0 + 32);
    }

    __syncthreads();
    *(short8*)&Asm[ar*40 + ah*16]     = sa0;
    *(short8*)&Asm[ar*40 + ah*16 + 8] = sa1;
    #pragma unroll
    for (int j = 0; j < 4; j++)
      *(short4v*)&Bsm[(mg*4 + j)*40 + kg*4] = bpk[j];
    __syncthreads();

    short8 afr[4], bfr[4];
    #pragma unroll
    for (int i = 0; i < 4; i++) afr[i] = *(const short8*)&Asm[(wc*64 + i*16 + r16)*40 + q*8];
    #pragma unroll
    for (int j = 0; j < 4; j++) bfr[j] = *(const short8*)&Bsm[(wsd*64 + j*16 + r16)*40 + q*8];
    #pragma unroll
    for (int i = 0; i < 4; i++)
      #pragma unroll
      for (int j = 0; j < 4; j++)
        acc[i][j] = __builtin_amdgcn_mfma_f32_16x16x32_bf16(afr[i], bfr[j], acc[i][j], 0, 0, 0);
  }

  // ---- LDS-transpose epilogue ----
  {
    float* Csm = (float*)SMEMraw;   // [32][132]
    #pragma unroll
    for (int qtr = 0; qtr < 4; qtr++){
      __syncthreads();
      if (wc == (qtr >> 1)){
        #pragma unroll
        for (int ii = 0; ii < 2; ii++){
          int i = (qtr & 1)*2 + ii;
          #pragma unroll
          for (int j = 0; j < 4; j++){
            int m = wsd*64 + j*16 + r16;
            #pragma unroll
            for (int rg = 0; rg < 4; rg++)
              Csm[(ii*16 + q*4 + rg)*132 + m] = acc[i][j][rg];
          }
        }
      }
      __syncthreads();
      #pragma unroll
      for (int sp = 0; sp < 2; sp++){
        int nrow = (t >> 4) + sp*16;
        int n = n0 + qtr*32 + nrow;
        int m8 = (t & 15)*8;
        if (n >= g.N) continue;
        int sg = s0 + m8;
        int b2 = sg / FL; int r2 = sg - b2*FL;
        if (b2 >= 2) continue;
        int f2 = (g.Fdim > 1) ? (r2 / g.Lw) : 0;
        int l2 = g.lq0 + (r2 - f2*g.Lw);
        float4v v0 = *(const float4v*)&Csm[nrow*132 + m8];
        float4v v1 = *(const float4v*)&Csm[nrow*132 + m8 + 4];
        long obase = ((long)(b2*g.Nsto + n)*g.Fdim + f2)*g.CLw + (l2 - g.Cl0);
        short8 o;
        if (EMODE == 1){
          #pragma unroll
          for (int e = 0; e < 4; e++){ o[e] = f2bf(v0[e]); o[e+4] = f2bf(v1[e]); }
        } else if (EMODE == 2){
          short8 axv = *(const short8*)&g.auxXH[((long)(b2*g.N + n)*g.Fdim + f2)*2048 + l2];
          const float* ivp = &g.invn[(b2*g.Fdim + f2)*2048 + l2];
          float4v iv0 = *(const float4v*)ivp;
          float4v iv1 = *(const float4v*)(ivp + 4);
          #pragma unroll
          for (int e = 0; e < 4; e++){
            float xn0 = bf2f((unsigned short)axv[e]) * iv0[e];
            float xn1 = bf2f((unsigned short)axv[e+4]) * iv1[e];
            o[e]   = f2bf((xn0*0.7f + v0[e]*0.3f)*MPS);
            o[e+4] = f2bf((xn1*0.7f + v1[e]*0.3f)*MPS);
          }
        } else { // EMODE == 3
          float pwn = g.pw[n], pbn = g.pb[n];
          const float* ap  = &g.audio[(b2*128 + f2)*2048 + l2];
          const float* ivp = &g.invn[(b2*g.Fdim + f2)*2048 + l2];
          float4v a0 = *(const float4v*)ap,  a1 = *(const float4v*)(ap + 4);
          float4v iv0 = *(const float4v*)ivp, iv1 = *(const float4v*)(ivp + 4);
          #pragma unroll
          for (int e = 0; e < 4; e++){
            float xn0 = (a0[e]*pwn + pbn)*iv0[e];
            float xn1 = (a1[e]*pwn + pbn)*iv1[e];
            o[e]   = f2bf((xn0*0.7f + v0[e]*0.3f)*MPS);
            o[e+4] = f2bf((xn1*0.7f + v1[e]*0.3f)*MPS);
          }
        }
        *(short8*)&g.CoutH[obase] = o;
      }
    }
  }
}

// ---------------- downsample conv GEMM: 64x64 tile on pooled P, prefetched ----------------
struct DnArgs {
  const unsigned short* A; const unsigned short* P;
  float* Cout; unsigned short* CoutH;
  int N, K, F2, Lc, l0;
};

template<int EMODE>
__global__ __launch_bounds__(256,4) void mgemm64_kernel(DnArgs g){
  __shared__ __align__(16) char SMEM[10240];
  unsigned short* Asm = (unsigned short*)SMEM;
  unsigned short* Bsm = Asm + 64*40;
  const int t = threadIdx.x;
  const int lane = t & 63;
  const int wave = t >> 6;
  const int wc = wave >> 1, wsd = wave & 1;
  const int q = lane >> 4, r16 = lane & 15;
  const int s0 = blockIdx.x * 64;
  const int n0 = blockIdx.y * 64;
  const int FL = g.F2 * g.Lc;

  const int ar = t >> 2, ah = t & 3;
  const unsigned short* Aptr = g.A + (long)(n0 + ar)*g.K + ah*8;
  const int kg = t & 7, mg = t >> 3;
  const bool bstage = (mg < 16);
  const int mb = s0 + (mg & 15)*4;
  const int bcol = mb / FL; const int rr = mb - bcol*FL;
  const int fcol = rr / g.Lc; const int li = rr - fcol*g.Lc;
  const unsigned short* bbase = g.P + ((long)(bcol*g.K)*g.F2 + fcol)*g.Lc + li;
  const long kstep = (long)g.F2 * g.Lc;

  float4v acc[2][2];
  #pragma unroll
  for (int i = 0; i < 2; i++)
    #pragma unroll
    for (int j = 0; j < 2; j++) acc[i][j] = (float4v){0.f,0.f,0.f,0.f};

  short8 pa = {0,0,0,0,0,0,0,0};
  short4v praw[4];
  #pragma unroll
  for (int i = 0; i < 4; i++) praw[i] = (short4v){0,0,0,0};

  auto ldA = [&](int kb){ pa = *(const short8*)(Aptr + kb); };
  auto ldB = [&](int kb){
    if (bstage){
      #pragma unroll
      for (int i = 0; i < 4; i++)
        praw[i] = *(const short4v*)(bbase + (long)(kb + kg*4 + i)*kstep);
    }
  };
  ldA(0); ldB(0);

  for (int k0 = 0; k0 < g.K; k0 += 32){
    short8 sa = pa;
    short4v bpk[4];
    #pragma unroll
    for (int j = 0; j < 4; j++){
      short4v p;
      #pragma unroll
      for (int i = 0; i < 4; i++) p[i] = praw[i][j];
      bpk[j] = p;
    }
    if (k0 + 32 < g.K){ ldA(k0 + 32); ldB(k0 + 32); }

    __syncthreads();
    *(short8*)&Asm[ar*40 + ah*8] = sa;
    if (bstage){
      #pragma unroll
      for (int j = 0; j < 4; j++)
        *(short4v*)&Bsm[((mg & 15)*4 + j)*40 + kg*4] = bpk[j];
    }
    __syncthreads();

    short8 afr[2], bfr[2];
    #pragma unroll
    for (int i = 0; i < 2; i++) afr[i] = *(const short8*)&Asm[(wc*32 + i*16 + r16)*40 + q*8];
    #pragma unroll
    for (int j = 0; j < 2; j++) bfr[j] = *(const short8*)&Bsm[(wsd*32 + j*16 + r16)*40 + q*8];
    #pragma unroll
    for (int i = 0; i < 2; i++)
      #pragma unroll
      for (int j = 0; j < 2; j++)
        acc[i][j] = __builtin_amdgcn_mfma_f32_16x16x32_bf16(afr[i], bfr[j], acc[i][j], 0, 0, 0);
  }

  // ---- LDS-transpose epilogue: quarters of 16 n-rows ----
  {
    float* Csm = (float*)SMEM;   // [16][68]
    const int b2 = s0 / FL; const int r20 = s0 - b2*FL;
    const int f2c = r20 / g.Lc; const int l2c = g.l0 + (r20 - f2c*g.Lc);
    #pragma unroll
    for (int nq = 0; nq < 4; nq++){
      __syncthreads();
      if (wc == (nq >> 1)){
        const int i = nq & 1;
        #pragma unroll
        for (int j = 0; j < 2; j++)
          #pragma unroll
          for (int rg = 0; rg < 4; rg++)
            Csm[(q*4 + rg)*68 + wsd*32 + j*16 + r16] = acc[i][j][rg];
      }
      __syncthreads();
      int nrow = t >> 4;
      int mq = (t & 15)*4;
      int n = n0 + nq*16 + nrow;
      float4v v = *(const float4v*)&Csm[nrow*68 + mq];
      long oidx = ((long)(b2*g.N + n)*g.F2 + f2c)*2048 + l2c + mq;
      if (EMODE == 0){
        *(float4v*)&g.Cout[oidx] = v;
      } else {
        short4v o = { f2bf(v[0]), f2bf(v[1]), f2bf(v[2]), f2bf(v[3]) };
        *(short4v*)&g.CoutH[oidx] = o;
      }
    }
  }
}

// ---------------- seq out GEMM: 64x64 tile, Fdim=1, prefetched ----------------
template<int EMODE>
__global__ __launch_bounds__(256,4) void seqout_kernel(const unsigned short* __restrict__ A,
                                                       const unsigned short* __restrict__ Bh,
                                                       const float* __restrict__ invn,
                                                       const float* __restrict__ auxX,
                                                       float* __restrict__ Cout, int K){
  __shared__ __align__(16) char SMEM[10240];
  unsigned short* Asm = (unsigned short*)SMEM;
  unsigned short* Bsm = Asm + 64*40;
  const int t = threadIdx.x;
  const int lane = t & 63;
  const int wave = t >> 6;
  const int wc = wave >> 1, wsd = wave & 1;
  const int q = lane >> 4, r16 = lane & 15;
  const int s0 = blockIdx.x * 64;
  const int n0 = blockIdx.y * 64;

  const int ar = t >> 2, ah = t & 3;
  const unsigned short* Aptr = A + (long)(n0 + ar)*K + ah*8;
  const int kg = t & 7, mg = t >> 3;
  const bool bstage = (mg < 16);
  const int mb = s0 + (mg & 15)*4;
  const int bcol = mb >> 11, lb = mb & 2047;
  const unsigned short* bbase = Bh + ((long)bcol*K)*2048 + lb;

  float4v acc[2][2];
  #pragma unroll
  for (int i = 0; i < 2; i++)
    #pragma unroll
    for (int j = 0; j < 2; j++) acc[i][j] = (float4v){0.f,0.f,0.f,0.f};

  short8 pa = {0,0,0,0,0,0,0,0};
  short4v praw[4];
  #pragma unroll
  for (int i = 0; i < 4; i++) praw[i] = (short4v){0,0,0,0};

  auto ldA = [&](int kb){ pa = *(const short8*)(Aptr + kb); };
  auto ldB = [&](int kb){
    if (bstage){
      #pragma unroll
      for (int i = 0; i < 4; i++)
        praw[i] = *(const short4v*)(bbase + (long)(kb + kg*4 + i)*2048);
    }
  };
  ldA(0); ldB(0);

  for (int k0 = 0; k0 < K; k0 += 32){
    short8 sa = pa;
    short4v bpk[4];
    #pragma unroll
    for (int j = 0; j < 4; j++){
      short4v p;
      #pragma unroll
      for (int i = 0; i < 4; i++) p[i] = praw[i][j];
      bpk[j] = p;
    }
    if (k0 + 32 < K){ ldA(k0 + 32); ldB(k0 + 32); }

    __syncthreads();
    *(short8*)&Asm[ar*40 + ah*8] = sa;
    if (bstage){
      #pragma unroll
      for (int j = 0; j < 4; j++)
        *(short4v*)&Bsm[((mg & 15)*4 + j)*40 + kg*4] = bpk[j];
    }
    __syncthreads();

    short8 afr[2], bfr[2];
    #pragma unroll
    for (int i = 0; i < 2; i++) afr[i] = *(const short8*)&Asm[(wc*32 + i*16 + r16)*40 + q*8];
    #pragma unroll
    for (int j = 0; j < 2; j++) bfr[j] = *(const short8*)&Bsm[(wsd*32 + j*16 + r16)*40 + q*8];
    #pragma unroll
    for (int i = 0; i < 2; i++)
      #pragma unroll
      for (int j = 0; j < 2; j++)
        acc[i][j] = __builtin_amdgcn_mfma_f32_16x16x32_bf16(afr[i], bfr[j], acc[i][j], 0, 0, 0);
  }

  // ---- LDS-transpose epilogue ----
  {
    float* Csm = (float*)SMEM;   // [16][68]
    const int b2 = s0 >> 11; const int l0b = s0 & 2047;
    #pragma unroll
    for (int nq = 0; nq < 4; nq++){
      __syncthreads();
      if (wc == (nq >> 1)){
        const int i = nq & 1;
        #pragma unroll
        for (int j = 0; j < 2; j++)
          #pragma unroll
          for (int rg = 0; rg < 4; rg++)
            Csm[(q*4 + rg)*68 + wsd*32 + j*16 + r16] = acc[i][j][rg];
      }
      __syncthreads();
      int nrow = t >> 4;
      int mq = (t & 15)*4;
      int n = n0 + nq*16 + nrow;
      int l = l0b + mq;
      float4v v = *(const float4v*)&Csm[nrow*68 + mq];
      float4v ax = *(const float4v*)&auxX[((long)b2*512 + n)*2048 + l];
      float4v iv = *(const float4v*)&invn[b2*2048 + l];
      float4v r;
      #pragma unroll
      for (int e = 0; e < 4; e++){
        float xn = ax[e]*iv[e];
        float rr = (xn*0.7f + v[e]*0.3f)*MPS;
        r[e] = (EMODE == 6) ? silu_g(rr) : rr;
      }
      *(float4v*)&Cout[((long)b2*512 + n)*2048 + l] = r;
    }
  }
}

// ---------------- freq-pool ----------------
__global__ __launch_bounds__(256) void poolf_kernel(const unsigned short* __restrict__ Hb,
                                                    unsigned short* __restrict__ P,
                                                    int F2, int s, int Lc, long total4){
  long i = blockIdx.x*256 + threadIdx.x;
  if (i >= total4) return;
  long e = i*4;
  int li = (int)(e % Lc); long r0 = e / Lc;
  int f2 = (int)(r0 % F2); long r = r0 / F2;
  const unsigned short* src = Hb + ((long)r*F2*s + (long)f2*s)*Lc + li;
  float a0=0,a1=0,a2=0,a3=0;
  for (int p = 0; p < s; p++){
    short4v u = *(const short4v*)(src + (long)p*Lc);
    a0 += bf2f((unsigned short)u[0]); a1 += bf2f((unsigned short)u[1]);
    a2 += bf2f((unsigned short)u[2]); a3 += bf2f((unsigned short)u[3]);
  }
  float inv = 1.f/(float)s;
  short4v o = { f2bf(a0*inv), f2bf(a1*inv), f2bf(a2*inv), f2bf(a3*inv) };
  *(short4v*)&P[((long)r*F2 + f2)*Lc + li] = o;
}

// ---------------- depthwise 5x3 conv (+ silu), 4f x 8l per thread ----------------
struct DwArgs { const unsigned short* R1; const unsigned short* wd; unsigned short* R2; int C, F, Lc, l0; };
__global__ __launch_bounds__(256) void dw2d_kernel(DwArgs a){
  int idx = blockIdx.x*256 + threadIdx.x;
  int Lq = a.Lc >> 3;
  int Fq = a.F >> 2;
  int total = 2*a.C*Fq*Lq;
  if (idx >= total) return;
  int lq = idx % Lq; int r = idx / Lq;
  int fq = r % Fq; r /= Fq;
  int c = r % a.C; int b = r / a.C;
  int f0 = fq*4;
  int labs = a.l0 + lq*8;
  int Lw = a.Lc + 8;
  const unsigned short* base = a.R1 + (long)((b*a.C + c)*a.F)*Lw + (labs - (a.l0 - 4));
  const unsigned short* w = a.wd + c*15;
  float W[5][3];
  #pragma unroll
  for (int tp = 0; tp < 5; tp++)
    #pragma unroll
    for (int j = 0; j < 3; j++) W[tp][j] = bf2f(w[tp*3 + j]);

  const bool llo = (labs > 0);
  const bool lhi = (labs + 8 < 2048);
  float acc[4][8];
  #pragma unroll
  for (int t = 0; t < 4; t++)
    #pragma unroll
    for (int j = 0; j < 8; j++) acc[t][j] = 0.f;

  #pragma unroll
  for (int r8 = 0; r8 < 8; r8++){
    int rrow = f0 - 2 + r8;
    if (rrow < 0 || rrow >= a.F) continue;
    const unsigned short* p = base + (long)rrow*Lw;
    short4v u0 = *(const short4v*)p;
    short4v u1 = *(const short4v*)(p + 4);
    float x[10];
    x[0] = llo ? bf2f(p[-1]) : 0.f;
    x[1] = bf2f((unsigned short)u0[0]); x[2] = bf2f((unsigned short)u0[1]);
    x[3] = bf2f((unsigned short)u0[2]); x[4] = bf2f((unsigned short)u0[3]);
    x[5] = bf2f((unsigned short)u1[0]); x[6] = bf2f((unsigned short)u1[1]);
    x[7] = bf2f((unsigned short)u1[2]); x[8] = bf2f((unsigned short)u1[3]);
    x[9] = lhi ? bf2f(p[8]) : 0.f;
    #pragma unroll
    for (int t = 0; t < 4; t++){
      const int df = r8 - 2 - t;
      if (df < -2 || df > 2) continue;
      float w0 = W[df+2][0], w1 = W[df+2][1], w2 = W[df+2][2];
      #pragma unroll
      for (int j = 0; j < 8; j++)
        acc[t][j] += w0*x[j] + w1*x[j+1] + w2*x[j+2];
    }
  }

  unsigned short* ob = a.R2 + ((long)((b*a.C + c)*a.F + f0))*a.Lc + (labs - a.l0);
  #pragma unroll
  for (int t = 0; t < 4; t++){
    short8 o;
    #pragma unroll
    for (int j = 0; j < 8; j++) o[j] = f2bf(silu_g(acc[t][j]));
    *(short8*)(ob + (long)t*a.Lc) = o;
  }
}

// ---------------- seq depthwise 3-tap (+ silu), transposed layouts ----------------
__global__ __launch_bounds__(256) void dwseqT_kernel(const unsigned short* __restrict__ HST,
                                                     const unsigned short* __restrict__ w,
                                                     unsigned short* __restrict__ H2T){
  int idx = blockIdx.x*256 + threadIdx.x;
  if (idx >= 2*2048*128) return;
  int c0 = (idx & 127) * 8; long bt = idx >> 7;
  int tt = (int)(bt & 2047);
  const unsigned short* base = HST + bt*1024 + c0;
  short8 zz = {0,0,0,0,0,0,0,0};
  short8 x1 = *(const short8*)base;
  short8 x0 = (tt > 0)    ? *(const short8*)(base - 1024) : zz;
  short8 x2 = (tt < 2047) ? *(const short8*)(base + 1024) : zz;
  const unsigned short* wp = w + c0*3;
  short8 o;
  #pragma unroll
  for (int j = 0; j < 8; j++){
    float w0 = bf2f(wp[3*j]), w1 = bf2f(wp[3*j+1]), w2 = bf2f(wp[3*j+2]);
    float v = w0*bf2f((unsigned short)x0[j]) + w1*bf2f((unsigned short)x1[j]) + w2*bf2f((unsigned short)x2[j]);
    o[j] = f2bf(silu_g(v));
  }
  *(short8*)&H2T[bt*1024 + c0] = o;
}

// ---------------- minGRU scan + gate (bf16 z/c), wave-shuffle scan ----------------
__global__ __launch_bounds__(256) void scan_kernel(const unsigned short* __restrict__ ZC, const unsigned short* __restrict__ G,
                                                   unsigned short* __restrict__ SC){
  int bc = blockIdx.x;
  int b = bc >> 10, c = bc & 1023;
  const unsigned short* zrow = ZC + ((long)(b*2048 + c))*2048;
  const unsigned short* crow = ZC + ((long)(b*2048 + 1024 + c))*2048;
  const unsigned short* grow = G + (long)bc*2048;
  unsigned short* orow = SC + (long)bc*2048;
  int tid = threadIdx.x;
  int t0 = tid*8;
  short8 zv = *(const short8*)&zrow[t0];
  short8 cv = *(const short8*)&crow[t0];
  float av[8], bv[8];
  float A = 1.f, Bv = 0.f;
  #pragma unroll
  for (int j = 0; j < 8; j++){
    float z = bf2f((unsigned short)zv[j]); float cval = bf2f((unsigned short)cv[j]);
    float zs = 1.f/(1.f + __expf(-z));
    float a = 1.f - zs; float bb = zs*cval;
    av[j] = a; bv[j] = bb;
    Bv = a*Bv + bb;
    A = a*A;
  }
  int lane = tid & 63, wv = tid >> 6;
  float iA = A, iB = Bv;
  #pragma unroll
  for (int off = 1; off < 64; off <<= 1){
    float pA = __shfl_up(iA, off);
    float pB = __shfl_up(iB, off);
    if (lane >= off){ iB = iA*pB + iB; iA = iA*pA; }
  }
  float exA = __shfl_up(iA, 1);
  float exB = __shfl_up(iB, 1);
  if (lane == 0){ exA = 1.f; exB = 0.f; }
  __shared__ float sWA[4], sWB[4];
  if (lane == 63){ sWA[wv] = iA; sWB[wv] = iB; }
  __syncthreads();
  float wpA = 1.f, wpB = 0.f;
  #pragma unroll
  for (int w = 0; w < 3; w++){
    if (w < wv){ wpB = sWA[w]*wpB + sWB[w]; wpA = wpA*sWA[w]; }
  }
  float h = exA*wpB + exB;
  short8 gv = *(const short8*)&grow[t0];
  short8 ov;
  #pragma unroll
  for (int j = 0; j < 8; j++){
    h = av[j]*h + bv[j];
    ov[j] = f2bf(h * silu_g(bf2f((unsigned short)gv[j])));
  }
  *(short8*)&orow[t0] = ov;
}

extern "C" void kernel_launch(void* const* d_in, const int* in_sizes, int n_in,
                              void* d_out, int out_size, void* d_ws, size_t ws_size,
                              hipStream_t stream) {
  const float* audio = (const float*)d_in[0];
  const float* pw = (const float*)d_in[1];
  const float* pb = (const float*)d_in[2];
  const float* cw1[3] = {(const float*)d_in[3], (const float*)d_in[7], (const float*)d_in[11]};
  const float* cwd[3] = {(const float*)d_in[4], (const float*)d_in[8], (const float*)d_in[12]};
  const float* cw2[3] = {(const float*)d_in[5], (const float*)d_in[9], (const float*)d_in[13]};
  const float* cdn[3] = {(const float*)d_in[6], (const float*)d_in[10], (const float*)d_in[14]};
  const float* hgw  = (const float*)d_in[15];
  const float* dww  = (const float*)d_in[16];
  const float* gruw = (const float*)d_in[17];
  const float* outw = (const float*)d_in[18];
  float* out = (float*)d_out;

  // ---- workspace layout (bytes) ----
  char* P0 = (char*)d_ws;
  float*          INVW = (float*)P0;                    P0 += 131072;     // S at [32000]
  unsigned short* WBF  = (unsigned short*)P0;           P0 += 30443776;
  float*          INVN = (float*)P0;                    P0 += 2097152;
  char*           XBZC = P0;                            P0 += 33554432;   // XB fallback / ZC bf16 (seq)
  unsigned short* IN1h = (unsigned short*)P0;           P0 += 33554432;
  unsigned short* IN2h = (unsigned short*)P0;           P0 += 16777216;
  float*          SEQ  = (float*)P0;                    P0 += 8388608;
  char*           ARENA = P0;
  long arenaBytes = (long)ws_size - (long)(P0 - (char*)d_ws);
  float* S = INVW + 32000;

  const float* wsrc[16] = {cw1[0],cwd[0],cw2[0],cdn[0], cw1[1],cwd[1],cw2[1],cdn[1],
                           cw1[2],cwd[2],cw2[2],cdn[2], hgw, dww, gruw, outw};
  int Os[16] = {128,128,64,128, 256,256,128,256, 512,512,256,512, 8192,4096,8192,2048};
  int Ks[16] = {64,15,128,64, 128,15,256,128, 256,15,512,256, 512,3,1024,1024};
  int wbfOff[16];
  {
    int wo = 0;
    for (int i = 0; i < 16; i++){ wbfOff[i] = wo; wo += Os[i]*Ks[i]; }
  }
  {
    NcArgs na;
    int rows = 0;
    for (int i = 0; i < 16; i++){
      na.e[i].w = wsrc[i]; na.e[i].O = Os[i]; na.e[i].K = Ks[i]; na.e[i].dstOff = wbfOff[i];
      rows += Os[i];
    }
    normcast_kernel<<<rows, 64, 0, stream>>>(na, WBF);
  }
  projstats_kernel<<<1, 64, 0, stream>>>(pw, pb, S);

  // ---- conv blocks ----
  int Cin_[3]  = {64,128,256};
  int Cmid_[3] = {128,256,512};
  int F_[3]    = {128,32,8};
  int s_[3]    = {4,4,8};
  const unsigned short* XinH[3] = {nullptr, IN1h, IN2h};
  unsigned short* XoutH[3] = {IN1h, IN2h, nullptr};
  int iW1[3]={0,4,8}, iWd[3]={1,5,9}, iW2[3]={2,6,10}, iDn[3]={3,7,11};

  for (int b = 0; b < 3; b++){
    int Cin = Cin_[b], Cmid = Cmid_[b], F = F_[b], s = s_[b];
    int F2 = F/s;

    // nc selection: b1/b2 try K-major (chunk + XBT in arena); fall back to old path.
    bool kmajor = false;
    int nc = 0;
    long xbtE = 2L*F*2056*Cin;                        // XBT element count
    if (b > 0){
      for (int c = 1; c <= 16; c <<= 1){
        long Lc_ = 2048/c;
        long bytes = 2L*(2L*Cmid*F*(Lc_+8) + 2L*Cmid*F*Lc_ + 2L*Cin*F*Lc_ + 2L*Cin*F2*Lc_ + xbtE);
        if (bytes <= arenaBytes){ nc = c; kmajor = true; break; }
      }
    }
    if (!kmajor){
      nc = 16;
      for (int c = 1; c <= 16; c <<= 1){
        long Lc_ = 2048/c;
        long bytes = 2L*(2L*Cmid*F*(Lc_+8) + 2L*Cmid*F*Lc_ + 2L*Cin*F*Lc_ + 2L*Cin*F2*Lc_);
        if (bytes <= arenaBytes){ nc = c; break; }
      }
    }
    int Lc = 2048/nc;
    unsigned short* XBT = (unsigned short*)ARENA;
    unsigned short* R1 = kmajor ? (XBT + xbtE) : (unsigned short*)ARENA;
    unsigned short* R2 = R1 + 2L*Cmid*F*(Lc+8);
    unsigned short* Hb = R2 + 2L*Cmid*F*Lc;
    unsigned short* Pb = Hb + 2L*Cin*F*Lc;
    unsigned short* XB = (unsigned short*)XBZC;

    if (b == 0){
      invn_audio_kernel<<<(2*128*2048/4+255)/256, 256, 0, stream>>>(audio, S, INVN);
    } else {
      int positions = 2*F*2048;
      invn_reduce_kernel<8,true><<<positions/32, 256, 0, stream>>>(XinH[b], INVN, Cin, F);
      if (kmajor){
        normxT_kernel<<<dim3(34, Cin/64, 2*F), 256, 0, stream>>>(XinH[b], INVN, XBT, Cin, F);
      } else {
        long total4 = (long)2*Cin*F*2048/4;
        applynorm_kernel<true,true><<<(int)((total4+255)/256), 256, 0, stream>>>(XinH[b], INVN, XB, Cin, F, total4);
      }
    }

    for (int ci = 0; ci < nc; ci++){
      int l0 = ci*Lc;
      // conv1: Cin -> Cmid on window [l0-4, l0+Lc+4) -> R1 bf16
      if (b == 0){
        GemmArgs ga{};
        ga.A = WBF + wbfOff[iW1[b]];
        ga.Bh = XB; ga.invn = INVN; ga.audio = audio; ga.pw = pw; ga.pb = pb;
        ga.CoutH = R1; ga.N = Cmid; ga.K = Cin; ga.Fdim = F; ga.Lw = Lc+8; ga.lq0 = l0-4;
        ga.BLw = 2048; ga.Bl0 = 0; ga.CLw = Lc+8; ga.Cl0 = l0-4; ga.Nsto = Cmid; ga.Fsrc = F;
        int M1 = 2*F*(Lc+8);
        dim3 g1((M1+127)/128, (Cmid+127)/128);
        mgemm_kernel<2,1><<<g1,256,0,stream>>>(ga);
      } else if (kmajor){
        GCArgs gc{ WBF + wbfOff[iW1[b]], XBT, R1, Cmid, Cin, F, Lc+8, l0 };
        dim3 g1((2*F*(Lc+8))/128, Cmid/128);
        gemmC_kernel<<<g1,256,0,stream>>>(gc);
      } else {
        GemmArgs ga{};
        ga.A = WBF + wbfOff[iW1[b]];
        ga.Bh = XB; ga.invn = INVN; ga.audio = audio; ga.pw = pw; ga.pb = pb;
        ga.CoutH = R1; ga.N = Cmid; ga.K = Cin; ga.Fdim = F; ga.Lw = Lc+8; ga.lq0 = l0-4;
        ga.BLw = 2048; ga.Bl0 = 0; ga.CLw = Lc+8; ga.Cl0 = l0-4; ga.Nsto = Cmid; ga.Fsrc = F;
        int M1 = 2*F*(Lc+8);
        dim3 g1((M1+127)/128, (Cmid+127)/128);
        mgemm_kernel<0,1><<<g1,256,0,stream>>>(ga);
      }
      // depthwise 5x3 + silu -> R2 bf16
      DwArgs da{R1, WBF + wbfOff[iWd[b]], R2, Cmid, F, Lc, l0};
      int tdw = 2*Cmid*(F/4)*(Lc/8);
      dw2d_kernel<<<(tdw+255)/256, 256, 0, stream>>>(da);
      // conv2 + mp_add -> Hb bf16
      GemmArgs gb{};
      gb.A = WBF + wbfOff[iW2[b]];
      gb.Bh = R2; gb.invn = INVN; gb.audio = audio; gb.pw = pw; gb.pb = pb; gb.auxXH = XinH[b];
      gb.CoutH = Hb; gb.N = Cin; gb.K = Cmid; gb.Fdim = F; gb.Lw = Lc; gb.lq0 = l0;
      gb.BLw = Lc; gb.Bl0 = l0; gb.CLw = Lc; gb.Cl0 = l0; gb.Nsto = Cin; gb.Fsrc = F;
      int M2 = 2*F*Lc;
      dim3 g2((M2+127)/128, (Cin+127)/128);
      if (b == 0) mgemm_kernel<0,3><<<g2,256,0,stream>>>(gb);
      else        mgemm_kernel<0,2><<<g2,256,0,stream>>>(gb);
      // freq-pool Hb -> Pb (bf16)
      long tp4 = (2L*Cin*F2*Lc)/4;
      poolf_kernel<<<(int)((tp4+255)/256), 256, 0, stream>>>(Hb, Pb, F2, s, Lc, tp4);
      // dn conv
      DnArgs dn{};
      dn.A = WBF + wbfOff[iDn[b]]; dn.P = Pb;
      dn.Cout = SEQ; dn.CoutH = XoutH[b];
      dn.N = Cmid; dn.K = Cin; dn.F2 = F2; dn.Lc = Lc; dn.l0 = l0;
      dim3 gdn((2*F2*Lc)/64, Cmid/64);
      if (b == 2) mgemm64_kernel<0><<<gdn,256,0,stream>>>(dn);
      else        mgemm64_kernel<1><<<gdn,256,0,stream>>>(dn);
    }
  }

  // ---- seq blocks ----
  unsigned short* XST = IN1h;
  unsigned short* HST = XST + 2097152;
  unsigned short* G   = HST + 4194304;
  unsigned short* H2T = G  + 4194304;
  unsigned short* SC  = H2T + 4194304;
  unsigned short* ZCh = (unsigned short*)XBZC;

  for (int i = 0; i < 4; i++){
    invn_reduce_kernel<16,false><<<4096/16, 256, 0, stream>>>(SEQ, INVN, 512, 1);
    normT_kernel<<<dim3(32,8,2), 256, 0, stream>>>(SEQ, INVN, XST);
    GTArgs gh{ WBF + wbfOff[12] + (long)i*2048*512, XST, HST, G, 2048, 512 };
    gemmT_kernel<1><<<dim3(32,16), 256, 0, stream>>>(gh);
    dwseqT_kernel<<<2048, 256, 0, stream>>>(HST, WBF + wbfOff[13] + i*1024*3, H2T);
    GTArgs gz{ WBF + wbfOff[14] + (long)i*2048*1024, H2T, ZCh, nullptr, 2048, 1024 };
    gemmT_kernel<0><<<dim3(32,16), 256, 0, stream>>>(gz);
    scan_kernel<<<2048,256,0,stream>>>(ZCh, G, SC);
    const unsigned short* oA = WBF + wbfOff[15] + (long)i*512*1024;
    if (i < 3) seqout_kernel<5><<<dim3(64,8),256,0,stream>>>(oA, SC, INVN, SEQ, SEQ, 1024);
    else       seqout_kernel<6><<<dim3(64,8),256,0,stream>>>(oA, SC, INVN, SEQ, out, 1024);
  }

  (void)in_sizes; (void)n_in; (void)out_size;
}